// Round 8
// baseline (255.116 us; speedup 1.0000x reference)
//
#include <hip/hip_runtime.h>

typedef __attribute__((ext_vector_type(4))) float f32x4;
typedef __attribute__((ext_vector_type(8))) short bf16x8;
typedef __attribute__((ext_vector_type(4))) unsigned short u16x4;
typedef __attribute__((ext_vector_type(8))) unsigned short u16x8;
typedef unsigned short u16;
typedef unsigned int u32;

// B=4 T=4096 C=1024 H=16 LS=256
#define M_  16384   // B*T
#define C_  1024
#define N1_ 3072    // 3C

__device__ __forceinline__ float bf2f(u16 u) {
  union { u32 i; float f; } v; v.i = ((u32)u) << 16; return v.f;
}
__device__ __forceinline__ u16 f2bf(float f) {
  union { float f; u32 i; } v; v.f = f;
  u32 r = v.i + 0x7fffu + ((v.i >> 16) & 1u);   // RN-even
  return (u16)(r >> 16);
}

__device__ __forceinline__ void gload16(const void* g, void* l) {
  __builtin_amdgcn_global_load_lds(
      (const __attribute__((address_space(1))) u32*)g,
      (__attribute__((address_space(3))) u32*)l, 16, 0, 0);
}

// ---------------- casts ----------------
__global__ __launch_bounds__(256) void cast_f32_bf16(const float* __restrict__ in,
                                                     u16* __restrict__ out) {
  size_t i = (size_t)blockIdx.x * 256 + threadIdx.x;
  f32x4 v = ((const f32x4*)in)[i];
  u16x4 o = { f2bf(v[0]), f2bf(v[1]), f2bf(v[2]), f2bf(v[3]) };
  ((u16x4*)out)[i] = o;
}

// in[K][N] fp32 -> out[N][K] bf16, LDS-tiled 64x64, coalesced both sides
__global__ __launch_bounds__(256) void transpose_cast(const float* __restrict__ in,
                                                      u16* __restrict__ out, int K, int N) {
  __shared__ u16 tile[64][65];
  const int n0 = blockIdx.x * 64, k0 = blockIdx.y * 64;
  const int tid = threadIdx.x;
  const int nn = tid & 63, kk = tid >> 6;
#pragma unroll
  for (int r = 0; r < 16; ++r)
    tile[kk * 16 + r][nn] = f2bf(in[(size_t)(k0 + kk * 16 + r) * N + n0 + nn]);
  __syncthreads();
  const int kc = tid & 15, nl = tid >> 4;
#pragma unroll
  for (int p = 0; p < 4; ++p) {
    const int n = p * 16 + nl;
    u16x4 v = { tile[kc * 4 + 0][n], tile[kc * 4 + 1][n],
                tile[kc * 4 + 2][n], tile[kc * 4 + 3][n] };
    *(u16x4*)(out + (size_t)(n0 + n) * K + k0 + kc * 4) = v;
  }
}

// ---------------- GEMM 256x256, BK=64, static-parity double buffer ----------------
__device__ __forceinline__ void store16(float* dst, f32x4 v0, f32x4 v1, f32x4 v2, f32x4 v3) {
  ((f32x4*)dst)[0] = v0; ((f32x4*)dst)[1] = v1; ((f32x4*)dst)[2] = v2; ((f32x4*)dst)[3] = v3;
}
__device__ __forceinline__ void store16(u16* dst, f32x4 v0, f32x4 v1, f32x4 v2, f32x4 v3) {
  u16x8 o0 = { f2bf(v0[0]), f2bf(v0[1]), f2bf(v0[2]), f2bf(v0[3]),
               f2bf(v1[0]), f2bf(v1[1]), f2bf(v1[2]), f2bf(v1[3]) };
  u16x8 o1 = { f2bf(v2[0]), f2bf(v2[1]), f2bf(v2[2]), f2bf(v2[3]),
               f2bf(v3[0]), f2bf(v3[1]), f2bf(v3[2]), f2bf(v3[3]) };
  *(u16x8*)dst = o0; *(u16x8*)(dst + 8) = o1;
}

// C = A * BT^T, bf16 in, fp32 acc. 512 thr (8 waves 2Mx4N). K=1024.
// AHB: A is head-blocked [bg][h][256][64] (row stride 64, K-tile step 16384).
// OUT=u16: C head-blocked QKV [part][bg][h][256][64] + ssq/ssk per-token partials.
// OUT=float: row-major C[M][N].
template <typename OUT, bool AHB>
__global__ __launch_bounds__(512, 2) void gemm256(const u16* __restrict__ A,
                                                  const u16* __restrict__ BT,
                                                  OUT* __restrict__ C,
                                                  int M, int N, int ntn,
                                                  float* __restrict__ ssq,
                                                  float* __restrict__ ssk) {
  constexpr int ARS   = AHB ? 64 : 1024;     // A row stride (elements)
  constexpr int ASTEP = AHB ? 16384 : 64;    // A K-tile step (elements)
  __shared__ __align__(16) u16 sA0[256 * 64], sA1[256 * 64];
  __shared__ __align__(16) u16 sB0[256 * 64], sB1[256 * 64];
  __shared__ float ssred[4][256];
  const int tid = threadIdx.x, lane = tid & 63, w = tid >> 6;
  const int wm = w >> 2, wn = w & 3;

  int bid = blockIdx.x;
  const int cpx = gridDim.x >> 3;              // grid % 8 == 0 for all our launches
  bid = (bid & 7) * cpx + (bid >> 3);          // XCD swizzle (T1)
  const int tm = (bid / ntn) << 8, tn = (bid % ntn) << 8;

  const u16* srcA[4]; const u16* srcB[4]; int ldsOff[4];
#pragma unroll
  for (int l = 0; l < 4; ++l) {
    const int g = l * 512 + tid;
    const int row = g >> 3, c = g & 7;
    srcA[l] = A + (size_t)tm * 1024 + (size_t)row * ARS + ((c ^ (row & 7)) << 3);
    srcB[l] = BT + (size_t)(tn + row) * 1024 + ((c ^ (row & 7)) << 3);
    ldsOff[l] = g << 4;
  }

#define STAGE(sa, sb, kt) do {                                                 \
    _Pragma("unroll") for (int _l = 0; _l < 4; ++_l) {                         \
      gload16(srcA[_l] + (kt) * ASTEP, (char*)(sa) + ldsOff[_l]);              \
      gload16(srcB[_l] + (kt) * 64, (char*)(sb) + ldsOff[_l]); } } while (0)

  const int swz = (lane & 7) << 4;
  const int r16 = lane & 15;
  const int kb = (lane >> 4) << 4;
#define LDA_(sa, fm, ks) (*(const bf16x8*)((const char*)(sa) + \
    (wm * 128 + (fm) * 16 + r16) * 128 + ((((ks) << 6) | kb) ^ swz)))
#define LDB_(sb, fn, ks) (*(const bf16x8*)((const char*)(sb) + \
    (wn * 64 + (fn) * 16 + r16) * 128 + ((((ks) << 6) | kb) ^ swz)))

  f32x4 acc[8][4];
#pragma unroll
  for (int i = 0; i < 8; ++i)
#pragma unroll
    for (int j = 0; j < 4; ++j) acc[i][j] = (f32x4){0.f, 0.f, 0.f, 0.f};

#define MM(i, j, a_, b_) acc[i][j] = __builtin_amdgcn_mfma_f32_16x16x32_bf16(a_, b_, acc[i][j], 0, 0, 0)

#define KTILE(sa, sb, ...) do {                                                \
  bf16x8 ka[4][2], kb0[2][2], kb1[2][2];                                       \
  _Pragma("unroll") for (int fm = 0; fm < 4; ++fm) {                           \
    ka[fm][0] = LDA_(sa, fm, 0); ka[fm][1] = LDA_(sa, fm, 1); }                \
  _Pragma("unroll") for (int fn = 0; fn < 2; ++fn) {                           \
    kb0[fn][0] = LDB_(sb, fn, 0); kb0[fn][1] = LDB_(sb, fn, 1); }              \
  __builtin_amdgcn_s_barrier();                                                \
  __builtin_amdgcn_s_setprio(1);                                               \
  _Pragma("unroll") for (int fm = 0; fm < 4; ++fm)                             \
    _Pragma("unroll") for (int fn = 0; fn < 2; ++fn) {                         \
      MM(fm, fn, ka[fm][0], kb0[fn][0]); MM(fm, fn, ka[fm][1], kb0[fn][1]); }  \
  __builtin_amdgcn_s_setprio(0);                                               \
  __builtin_amdgcn_s_barrier();                                                \
  _Pragma("unroll") for (int fn = 0; fn < 2; ++fn) {                           \
    kb1[fn][0] = LDB_(sb, 2 + fn, 0); kb1[fn][1] = LDB_(sb, 2 + fn, 1); }      \
  __builtin_amdgcn_s_barrier();                                                \
  __builtin_amdgcn_s_setprio(1);                                               \
  _Pragma("unroll") for (int fm = 0; fm < 4; ++fm)                             \
    _Pragma("unroll") for (int fn = 0; fn < 2; ++fn) {                         \
      MM(fm, 2 + fn, ka[fm][0], kb1[fn][0]); MM(fm, 2 + fn, ka[fm][1], kb1[fn][1]); } \
  __builtin_amdgcn_s_setprio(0);                                               \
  __builtin_amdgcn_s_barrier();                                                \
  _Pragma("unroll") for (int fm = 0; fm < 4; ++fm) {                           \
    ka[fm][0] = LDA_(sa, 4 + fm, 0); ka[fm][1] = LDA_(sa, 4 + fm, 1); }        \
  __builtin_amdgcn_s_barrier();                                                \
  __builtin_amdgcn_s_setprio(1);                                               \
  _Pragma("unroll") for (int fm = 0; fm < 4; ++fm)                             \
    _Pragma("unroll") for (int fn = 0; fn < 2; ++fn) {                         \
      MM(4 + fm, 2 + fn, ka[fm][0], kb1[fn][0]); MM(4 + fm, 2 + fn, ka[fm][1], kb1[fn][1]); } \
  __builtin_amdgcn_s_setprio(0);                                               \
  __builtin_amdgcn_s_barrier();                                                \
  __builtin_amdgcn_sched_barrier(0);                                           \
  __VA_ARGS__;                                                                 \
  __builtin_amdgcn_s_setprio(1);                                               \
  _Pragma("unroll") for (int fm = 0; fm < 4; ++fm)                             \
    _Pragma("unroll") for (int fn = 0; fn < 2; ++fn) {                         \
      MM(4 + fm, fn, ka[fm][0], kb0[fn][0]); MM(4 + fm, fn, ka[fm][1], kb0[fn][1]); } \
  __builtin_amdgcn_s_setprio(0);                                               \
} while (0)

#define TILE_ENTRY(vm) do { __builtin_amdgcn_sched_barrier(0);                 \
    asm volatile("s_waitcnt vmcnt(" #vm ")");                                  \
    __builtin_amdgcn_sched_barrier(0);                                         \
    __builtin_amdgcn_s_barrier();                                              \
    __builtin_amdgcn_sched_barrier(0); } while (0)

  STAGE(sA0, sB0, 0);
  STAGE(sA1, sB1, 1);

#pragma unroll 1
  for (int i = 0; i < 7; ++i) {
    TILE_ENTRY(8);
    KTILE(sA0, sB0, STAGE(sA0, sB0, 2 * i + 2));
    TILE_ENTRY(8);
    KTILE(sA1, sB1, STAGE(sA1, sB1, 2 * i + 3));
  }
  TILE_ENTRY(8);
  KTILE(sA0, sB0, (void)0);
  TILE_ENTRY(0);
  KTILE(sA1, sB1, (void)0);

  __syncthreads();

  const int part = tn >> 10;                  // 0=q 1=k 2=v
  const int cp = tn & 1023;
  const int bg = tm >> 8;
  const int hh = (cp >> 6) + wn;

  // ---- epilogue: per-wave LDS repack -> coalesced wide stores; ss fused ----
  u16* eb = (w == 0) ? sA0 : (w == 1) ? sA0 + 8192 : (w == 2) ? sA1 : (w == 3) ? sA1 + 8192
          : (w == 4) ? sB0 : (w == 5) ? sB0 + 8192 : (w == 6) ? sB1 : sB1 + 8192;
  float* fb = (float*)eb;                     // 16 x 68 f32 region per wave
  const int erow = lane >> 2, eseg = lane & 3;
  OUT* dstb;
  if constexpr (sizeof(OUT) == 2)
    dstb = C + (size_t)part * ((size_t)M_ * C_) + ((size_t)(bg * 16 + hh) * 256) * 64;
  else
    dstb = C + (size_t)tm * N + tn + wn * 64;
#pragma unroll
  for (int fm = 0; fm < 8; ++fm) {
#pragma unroll
    for (int fn = 0; fn < 4; ++fn)
#pragma unroll
      for (int r = 0; r < 4; ++r)
        fb[((lane >> 4) * 4 + r) * 68 + fn * 16 + (lane & 15)] = acc[fm][fn][r];
    asm volatile("s_waitcnt lgkmcnt(0)" ::: "memory");
    const float* src = &fb[erow * 68 + eseg * 16];
    f32x4 v0 = ((const f32x4*)src)[0], v1 = ((const f32x4*)src)[1];
    f32x4 v2 = ((const f32x4*)src)[2], v3 = ((const f32x4*)src)[3];
    if constexpr (sizeof(OUT) == 2) {
      if (part < 2) {                          // ss partial from repacked values
        float s = 0.f;
#pragma unroll
        for (int e = 0; e < 4; ++e)
          s += v0[e] * v0[e] + v1[e] * v1[e] + v2[e] * v2[e] + v3[e] * v3[e];
        s += __shfl_xor(s, 1, 64);
        s += __shfl_xor(s, 2, 64);
        if ((lane & 3) == 0) ssred[wn][wm * 128 + fm * 16 + erow] = s;
      }
    }
    OUT* dst;
    if constexpr (sizeof(OUT) == 2)
      dst = dstb + (size_t)(wm * 128 + fm * 16 + erow) * 64 + eseg * 16;
    else
      dst = dstb + (size_t)(wm * 128 + fm * 16 + erow) * N + eseg * 16;
    store16(dst, v0, v1, v2, v3);
  }
  if constexpr (sizeof(OUT) == 2) {
    if (part < 2) {
      __syncthreads();
      if (tid < 256) {
        float s = ssred[0][tid] + ssred[1][tid] + ssred[2][tid] + ssred[3][tid];
        (part == 0 ? ssq : ssk)[(size_t)(tm + tid) * 4 + (cp >> 8)] = s;
      }
    }
  }
#undef STAGE
#undef LDA_
#undef LDB_
#undef MM
#undef KTILE
#undef TILE_ENTRY
}

// ---------------- block-causal attention (chunked online softmax) ----------------
// grid 1024 = (bg, h). 256 thr (4 waves). LDS 49.3KB, VGPR target ~130 (cap 170)
// -> 3 blocks/CU. Inner loop: 4 KV-chunks of 64, online max/sum with
// __all-guarded rescale; s[] shrinks 16->4 f32x4 (the round-7 register hog).
// Masked scores -> exp(-3e38-m)=0, so no zero-padding needed.
__global__ __launch_bounds__(256, 3) void attn_kernel(const u16* __restrict__ qkvblk,
                                                      const float* __restrict__ ssq,
                                                      const float* __restrict__ ssk,
                                                      const float* __restrict__ lnw,
                                                      u16* __restrict__ y) {
  const int bid = blockIdx.x;
  const int h = bid & 15;
  const int bg = bid >> 4;
  const size_t rowbase = (size_t)bg * 256;
  const u16* Qb = qkvblk + ((size_t)(bg * 16 + h) * 256) * 64;
  const u16* Kb = Qb + (size_t)M_ * C_;
  const u16* Vb = Qb + 2 * (size_t)M_ * C_;
  u16* Yb = y + ((size_t)(bg * 16 + h) * 256) * 64;

  __shared__ __align__(16) u16 Vt[64 * 256];      // 32KB [hd][k_tok], swizzled
  __shared__ __align__(16) u16 Ps[4][16 * 128];   // 4KB/wave P-chunk / y repack
  __shared__ float kscl[256];
  __shared__ float lnsq[64];

  const int tid = threadIdx.x;
  const int lane = tid & 63;
  const int w = tid >> 6;
  const int g = lane >> 4;
  const int qi = lane & 15;

  // ---- stage V (scatter-transpose) + per-token k scales + head lnw^2 ----
  {
    const int r = tid;
    const u16* vr = Vb + (size_t)r * 64;
#pragma unroll
    for (int j = 0; j < 8; ++j) {
      bf16x8 vv = *(const bf16x8*)(vr + j * 8);
#pragma unroll
      for (int e = 0; e < 8; ++e) {
        int d = j * 8 + e;
        *(u16*)((char*)Vt + d * 512 + ((2 * r) ^ ((d & 7) << 4))) = (u16)vv[e];
      }
    }
    f32x4 kp = ((const f32x4*)ssk)[rowbase + r];
    kscl[r] = rsqrtf((kp[0] + kp[1] + kp[2] + kp[3]) * (1.0f / 1024.0f) + 1e-6f);
    if (tid < 64) { float a = lnw[h * 64 + tid]; lnsq[tid] = a * a; }
  }
  __syncthreads();

  char* pb = (char*)Ps[w];
  const int swq = (qi & 7) << 4;

  auto body = [&](int qt) {
    const int q = qt * 16 + qi;

    // Q fragment + rms scale + lnw^2 (per body; latency hidden by 12 waves/CU)
    f32x4 qv = ((const f32x4*)ssq)[rowbase + q];
    const u16* qrow = Qb + (size_t)q * 64 + g * 8;
    bf16x8 q0 = *(const bf16x8*)(qrow);
    bf16x8 q1 = *(const bf16x8*)(qrow + 32);
    {
      const float qsc = rsqrtf((qv[0] + qv[1] + qv[2] + qv[3]) * (1.0f / 1024.0f) + 1e-6f);
      f32x4 wa0 = *(const f32x4*)&lnsq[g * 8],      wa1 = *(const f32x4*)&lnsq[g * 8 + 4];
      f32x4 wb0 = *(const f32x4*)&lnsq[32 + g * 8], wb1 = *(const f32x4*)&lnsq[32 + g * 8 + 4];
#pragma unroll
      for (int e = 0; e < 4; ++e) {
        q0[e]     = (short)f2bf(bf2f((u16)q0[e]) * qsc * wa0[e]);
        q0[4 + e] = (short)f2bf(bf2f((u16)q0[4 + e]) * qsc * wa1[e]);
        q1[e]     = (short)f2bf(bf2f((u16)q1[e]) * qsc * wb0[e]);
        q1[4 + e] = (short)f2bf(bf2f((u16)q1[4 + e]) * qsc * wb1[e]);
      }
    }

    float m_run = -3e38f, sum = 0.f;
    f32x4 yacc[4];
#pragma unroll
    for (int dn = 0; dn < 4; ++dn) yacc[dn] = (f32x4){0.f, 0.f, 0.f, 0.f};

#pragma unroll
    for (int c = 0; c < 4; ++c) if (c * 4 <= qt) {
      // ---- QK for chunk c (n = 4c..4c+3) ----
      f32x4 s[4];
#pragma unroll
      for (int nl = 0; nl < 4; ++nl) {
        const int n = c * 4 + nl;
        if (n <= qt) {
          const u16* krow = Kb + (size_t)(n * 16 + qi) * 64 + g * 8;
          bf16x8 ka0 = *(const bf16x8*)(krow);
          bf16x8 ka1 = *(const bf16x8*)(krow + 32);
          f32x4 a = {0.f, 0.f, 0.f, 0.f};
          a = __builtin_amdgcn_mfma_f32_16x16x32_bf16(ka0, q0, a, 0, 0, 0);
          a = __builtin_amdgcn_mfma_f32_16x16x32_bf16(ka1, q1, a, 0, 0, 0);
          s[nl] = a;
        } else {
          s[nl] = (f32x4){-3e38f, -3e38f, -3e38f, -3e38f};
        }
      }
      // ---- scale, mask, chunk max ----
      float mc = -3e38f;
#pragma unroll
      for (int nl = 0; nl < 4; ++nl) {
        const int n = c * 4 + nl;
        f32x4 k4 = *(const f32x4*)&kscl[n * 16 + g * 4];
#pragma unroll
        for (int r = 0; r < 4; ++r) {
          const int k_abs = n * 16 + g * 4 + r;
          float v = (n <= qt) ? s[nl][r] * 0.125f * k4[r] : -3e38f;
          v = (k_abs <= q) ? v : -3e38f;
          s[nl][r] = v;
          mc = fmaxf(mc, v);
        }
      }
      mc = fmaxf(mc, __shfl_xor(mc, 16, 64));
      mc = fmaxf(mc, __shfl_xor(mc, 32, 64));
      // ---- online rescale (skipped when no lane's max grew) ----
      if (!__all(mc <= m_run)) {
        const float m_new = fmaxf(m_run, mc);
        const float sc = __expf(m_run - m_new);   // 0 on first chunk
        sum *= sc;
        const float s0 = __shfl(sc, g * 4 + 0, 64);
        const float s1 = __shfl(sc, g * 4 + 1, 64);
        const float s2 = __shfl(sc, g * 4 + 2, 64);
        const float s3 = __shfl(sc, g * 4 + 3, 64);
#pragma unroll
        for (int dn = 0; dn < 4; ++dn) {
          yacc[dn][0] *= s0; yacc[dn][1] *= s1;
          yacc[dn][2] *= s2; yacc[dn][3] *= s3;
        }
        m_run = m_new;
      }
      // ---- exp + P write (always all 4 quads; masked -> 0) ----
#pragma unroll
      for (int nl = 0; nl < 4; ++nl) {
        u16x4 pk;
#pragma unroll
        for (int r = 0; r < 4; ++r) {
          float p = __expf(s[nl][r] - m_run);
          sum += p;
          pk[r] = f2bf(p);
        }
        *(u16x4*)(pb + qi * 256 + ((nl * 32 + g * 8) ^ swq)) = pk;
      }
      // ---- PV for chunk (per-wave private LDS; compiler inserts lgkmcnt) ----
#pragma unroll
      for (int kfl = 0; kfl < 2; ++kfl) {
        bf16x8 pa = *(const bf16x8*)(pb + qi * 256 + ((kfl * 64 + g * 16) ^ swq));
        const int kglob = (c * 2 + kfl) * 64 + g * 16;
#pragma unroll
        for (int dn = 0; dn < 4; ++dn) {
          const int d = dn * 16 + qi;
          bf16x8 vb = *(const bf16x8*)((const char*)Vt + d * 512 + (kglob ^ swq));
          yacc[dn] = __builtin_amdgcn_mfma_f32_16x16x32_bf16(pa, vb, yacc[dn], 0, 0, 0);
        }
      }
    }

    // ---- final row-sum across g ----
    sum += __shfl_xor(sum, 16, 64);
    sum += __shfl_xor(sum, 32, 64);

    // ---- y repack through pb (private) -> fully contiguous stores ----
#pragma unroll
    for (int r = 0; r < 4; ++r) {
      const float inv = 1.0f / __shfl(sum, g * 4 + r, 64);
      const int row = g * 4 + r;
#pragma unroll
      for (int dn = 0; dn < 4; ++dn)
        *(u16*)(pb + row * 128 + ((dn * 32 + qi * 2) ^ ((row & 7) << 4))) =
            f2bf(yacc[dn][r] * inv);
    }
#pragma unroll
    for (int half = 0; half < 2; ++half) {
      const int row = half * 8 + (lane >> 3);
      const int c16 = lane & 7;
      u16x8 v = *(const u16x8*)(pb + row * 128 + ((c16 * 16) ^ ((row & 7) << 4)));
      *(u16x8*)(Yb + (size_t)(qt * 16 + row) * 64 + c16 * 8) = v;
    }
  };

  // balanced tile set {w, 7-w, 8+w, 15-w}: equal causal work per wave
  body(w);
  body(7 - w);
  body(8 + w);
  body(15 - w);
}

// ---------------- launch ----------------
extern "C" void kernel_launch(void* const* d_in, const int* in_sizes, int n_in,
                              void* d_out, int out_size, void* d_ws, size_t ws_size,
                              hipStream_t stream) {
  const float* x      = (const float*)d_in[0];   // [16384][1024]
  const float* w_qkv  = (const float*)d_in[1];   // [1024][3072]
  const float* ln_w   = (const float*)d_in[2];   // [1024]
  const float* w_proj = (const float*)d_in[3];   // [1024][1024]
  float* out = (float*)d_out;                    // [16384][1024] fp32

  u16* xb     = (u16*)d_ws;                          // 16384*1024
  u16* wqkvT  = xb + (size_t)M_ * C_;                // 3072*1024 (transposed)
  u16* wprojT = wqkvT + (size_t)N1_ * C_;            // 1024*1024 (transposed)
  u16* qkvblk = wprojT + (size_t)C_ * C_;            // 3 * 16384*1024 head-blocked
  u16* yb     = qkvblk + 3 * (size_t)M_ * C_;        // 16384*1024 head-blocked
  float* ssq  = (float*)(yb + (size_t)M_ * C_);      // 16384*4 f32
  float* ssk  = ssq + (size_t)M_ * 4;                // 16384*4 f32

  cast_f32_bf16<<<(M_ * C_) / 1024, 256, 0, stream>>>(x, xb);
  transpose_cast<<<dim3(N1_ / 64, C_ / 64), 256, 0, stream>>>(w_qkv, wqkvT, C_, N1_);
  transpose_cast<<<dim3(C_ / 64, C_ / 64), 256, 0, stream>>>(w_proj, wprojT, C_, C_);

  gemm256<u16, false><<<(M_ / 256) * (N1_ / 256), 512, 0, stream>>>(
      xb, wqkvT, qkvblk, M_, N1_, N1_ / 256, ssq, ssk);
  attn_kernel<<<64 * 16, 256, 0, stream>>>(qkvblk, ssq, ssk, ln_w, yb);
  gemm256<float, true><<<(M_ / 256) * (C_ / 256), 512, 0, stream>>>(
      yb, wprojT, out, M_, C_, C_ / 256, nullptr, nullptr);
}

// Round 9
// 241.381 us; speedup vs baseline: 1.0569x; 1.0569x over previous
//
#include <hip/hip_runtime.h>

typedef __attribute__((ext_vector_type(4))) float f32x4;
typedef __attribute__((ext_vector_type(8))) short bf16x8;
typedef __attribute__((ext_vector_type(4))) unsigned short u16x4;
typedef __attribute__((ext_vector_type(8))) unsigned short u16x8;
typedef unsigned short u16;
typedef unsigned int u32;

// B=4 T=4096 C=1024 H=16 LS=256
#define M_  16384   // B*T
#define C_  1024
#define N1_ 3072    // 3C

__device__ __forceinline__ float bf2f(u16 u) {
  union { u32 i; float f; } v; v.i = ((u32)u) << 16; return v.f;
}
__device__ __forceinline__ u16 f2bf(float f) {
  union { float f; u32 i; } v; v.f = f;
  u32 r = v.i + 0x7fffu + ((v.i >> 16) & 1u);   // RN-even
  return (u16)(r >> 16);
}

__device__ __forceinline__ void gload16(const void* g, void* l) {
  __builtin_amdgcn_global_load_lds(
      (const __attribute__((address_space(1))) u32*)g,
      (__attribute__((address_space(3))) u32*)l, 16, 0, 0);
}

// ---------------- casts ----------------
__global__ __launch_bounds__(256) void cast_f32_bf16(const float* __restrict__ in,
                                                     u16* __restrict__ out) {
  size_t i = (size_t)blockIdx.x * 256 + threadIdx.x;
  f32x4 v = ((const f32x4*)in)[i];
  u16x4 o = { f2bf(v[0]), f2bf(v[1]), f2bf(v[2]), f2bf(v[3]) };
  ((u16x4*)out)[i] = o;
}

// in[K][N] fp32 -> out[N][K] bf16, LDS-tiled 64x64, coalesced both sides
__global__ __launch_bounds__(256) void transpose_cast(const float* __restrict__ in,
                                                      u16* __restrict__ out, int K, int N) {
  __shared__ u16 tile[64][65];
  const int n0 = blockIdx.x * 64, k0 = blockIdx.y * 64;
  const int tid = threadIdx.x;
  const int nn = tid & 63, kk = tid >> 6;
#pragma unroll
  for (int r = 0; r < 16; ++r)
    tile[kk * 16 + r][nn] = f2bf(in[(size_t)(k0 + kk * 16 + r) * N + n0 + nn]);
  __syncthreads();
  const int kc = tid & 15, nl = tid >> 4;
#pragma unroll
  for (int p = 0; p < 4; ++p) {
    const int n = p * 16 + nl;
    u16x4 v = { tile[kc * 4 + 0][n], tile[kc * 4 + 1][n],
                tile[kc * 4 + 2][n], tile[kc * 4 + 3][n] };
    *(u16x4*)(out + (size_t)(n0 + n) * K + k0 + kc * 4) = v;
  }
}

// ---------------- GEMM 256x256, BK=64, static-parity double buffer ----------------
__device__ __forceinline__ void store16(float* dst, f32x4 v0, f32x4 v1, f32x4 v2, f32x4 v3) {
  ((f32x4*)dst)[0] = v0; ((f32x4*)dst)[1] = v1; ((f32x4*)dst)[2] = v2; ((f32x4*)dst)[3] = v3;
}
__device__ __forceinline__ void store16(u16* dst, f32x4 v0, f32x4 v1, f32x4 v2, f32x4 v3) {
  u16x8 o0 = { f2bf(v0[0]), f2bf(v0[1]), f2bf(v0[2]), f2bf(v0[3]),
               f2bf(v1[0]), f2bf(v1[1]), f2bf(v1[2]), f2bf(v1[3]) };
  u16x8 o1 = { f2bf(v2[0]), f2bf(v2[1]), f2bf(v2[2]), f2bf(v2[3]),
               f2bf(v3[0]), f2bf(v3[1]), f2bf(v3[2]), f2bf(v3[3]) };
  *(u16x8*)dst = o0; *(u16x8*)(dst + 8) = o1;
}

// C = A * BT^T, bf16 in, fp32 acc. 512 thr (8 waves 2Mx4N). K=1024.
// AHB: A is head-blocked [bg][h][256][64] (row stride 64, K-tile step 16384).
// OUT=u16: C head-blocked QKV [part][bg][h][256][64] + ssq/ssk per-token partials.
// OUT=float: row-major C[M][N].
template <typename OUT, bool AHB>
__global__ __launch_bounds__(512, 2) void gemm256(const u16* __restrict__ A,
                                                  const u16* __restrict__ BT,
                                                  OUT* __restrict__ C,
                                                  int M, int N, int ntn,
                                                  float* __restrict__ ssq,
                                                  float* __restrict__ ssk) {
  constexpr int ARS   = AHB ? 64 : 1024;     // A row stride (elements)
  constexpr int ASTEP = AHB ? 16384 : 64;    // A K-tile step (elements)
  __shared__ __align__(16) u16 sA0[256 * 64], sA1[256 * 64];
  __shared__ __align__(16) u16 sB0[256 * 64], sB1[256 * 64];
  __shared__ float ssred[4][256];
  const int tid = threadIdx.x, lane = tid & 63, w = tid >> 6;
  const int wm = w >> 2, wn = w & 3;

  int bid = blockIdx.x;
  const int cpx = gridDim.x >> 3;              // grid % 8 == 0 for all our launches
  bid = (bid & 7) * cpx + (bid >> 3);          // XCD swizzle (T1)
  const int tm = (bid / ntn) << 8, tn = (bid % ntn) << 8;

  const u16* srcA[4]; const u16* srcB[4]; int ldsOff[4];
#pragma unroll
  for (int l = 0; l < 4; ++l) {
    const int g = l * 512 + tid;
    const int row = g >> 3, c = g & 7;
    srcA[l] = A + (size_t)tm * 1024 + (size_t)row * ARS + ((c ^ (row & 7)) << 3);
    srcB[l] = BT + (size_t)(tn + row) * 1024 + ((c ^ (row & 7)) << 3);
    ldsOff[l] = g << 4;
  }

#define STAGE(sa, sb, kt) do {                                                 \
    _Pragma("unroll") for (int _l = 0; _l < 4; ++_l) {                         \
      gload16(srcA[_l] + (kt) * ASTEP, (char*)(sa) + ldsOff[_l]);              \
      gload16(srcB[_l] + (kt) * 64, (char*)(sb) + ldsOff[_l]); } } while (0)

  const int swz = (lane & 7) << 4;
  const int r16 = lane & 15;
  const int kb = (lane >> 4) << 4;
#define LDA_(sa, fm, ks) (*(const bf16x8*)((const char*)(sa) + \
    (wm * 128 + (fm) * 16 + r16) * 128 + ((((ks) << 6) | kb) ^ swz)))
#define LDB_(sb, fn, ks) (*(const bf16x8*)((const char*)(sb) + \
    (wn * 64 + (fn) * 16 + r16) * 128 + ((((ks) << 6) | kb) ^ swz)))

  f32x4 acc[8][4];
#pragma unroll
  for (int i = 0; i < 8; ++i)
#pragma unroll
    for (int j = 0; j < 4; ++j) acc[i][j] = (f32x4){0.f, 0.f, 0.f, 0.f};

#define MM(i, j, a_, b_) acc[i][j] = __builtin_amdgcn_mfma_f32_16x16x32_bf16(a_, b_, acc[i][j], 0, 0, 0)

#define KTILE(sa, sb, ...) do {                                                \
  bf16x8 ka[4][2], kb0[2][2], kb1[2][2];                                       \
  _Pragma("unroll") for (int fm = 0; fm < 4; ++fm) {                           \
    ka[fm][0] = LDA_(sa, fm, 0); ka[fm][1] = LDA_(sa, fm, 1); }                \
  _Pragma("unroll") for (int fn = 0; fn < 2; ++fn) {                           \
    kb0[fn][0] = LDB_(sb, fn, 0); kb0[fn][1] = LDB_(sb, fn, 1); }              \
  __builtin_amdgcn_s_barrier();                                                \
  __builtin_amdgcn_s_setprio(1);                                               \
  _Pragma("unroll") for (int fm = 0; fm < 4; ++fm)                             \
    _Pragma("unroll") for (int fn = 0; fn < 2; ++fn) {                         \
      MM(fm, fn, ka[fm][0], kb0[fn][0]); MM(fm, fn, ka[fm][1], kb0[fn][1]); }  \
  __builtin_amdgcn_s_setprio(0);                                               \
  __builtin_amdgcn_s_barrier();                                                \
  _Pragma("unroll") for (int fn = 0; fn < 2; ++fn) {                           \
    kb1[fn][0] = LDB_(sb, 2 + fn, 0); kb1[fn][1] = LDB_(sb, 2 + fn, 1); }      \
  __builtin_amdgcn_s_barrier();                                                \
  __builtin_amdgcn_s_setprio(1);                                               \
  _Pragma("unroll") for (int fm = 0; fm < 4; ++fm)                             \
    _Pragma("unroll") for (int fn = 0; fn < 2; ++fn) {                         \
      MM(fm, 2 + fn, ka[fm][0], kb1[fn][0]); MM(fm, 2 + fn, ka[fm][1], kb1[fn][1]); } \
  __builtin_amdgcn_s_setprio(0);                                               \
  __builtin_amdgcn_s_barrier();                                                \
  _Pragma("unroll") for (int fm = 0; fm < 4; ++fm) {                           \
    ka[fm][0] = LDA_(sa, 4 + fm, 0); ka[fm][1] = LDA_(sa, 4 + fm, 1); }        \
  __builtin_amdgcn_s_barrier();                                                \
  __builtin_amdgcn_s_setprio(1);                                               \
  _Pragma("unroll") for (int fm = 0; fm < 4; ++fm)                             \
    _Pragma("unroll") for (int fn = 0; fn < 2; ++fn) {                         \
      MM(4 + fm, 2 + fn, ka[fm][0], kb1[fn][0]); MM(4 + fm, 2 + fn, ka[fm][1], kb1[fn][1]); } \
  __builtin_amdgcn_s_setprio(0);                                               \
  __builtin_amdgcn_s_barrier();                                                \
  __builtin_amdgcn_sched_barrier(0);                                           \
  __VA_ARGS__;                                                                 \
  __builtin_amdgcn_s_setprio(1);                                               \
  _Pragma("unroll") for (int fm = 0; fm < 4; ++fm)                             \
    _Pragma("unroll") for (int fn = 0; fn < 2; ++fn) {                         \
      MM(4 + fm, fn, ka[fm][0], kb0[fn][0]); MM(4 + fm, fn, ka[fm][1], kb0[fn][1]); } \
  __builtin_amdgcn_s_setprio(0);                                               \
} while (0)

#define TILE_ENTRY(vm) do { __builtin_amdgcn_sched_barrier(0);                 \
    asm volatile("s_waitcnt vmcnt(" #vm ")");                                  \
    __builtin_amdgcn_sched_barrier(0);                                         \
    __builtin_amdgcn_s_barrier();                                              \
    __builtin_amdgcn_sched_barrier(0); } while (0)

  STAGE(sA0, sB0, 0);
  STAGE(sA1, sB1, 1);

#pragma unroll 1
  for (int i = 0; i < 7; ++i) {
    TILE_ENTRY(8);
    KTILE(sA0, sB0, STAGE(sA0, sB0, 2 * i + 2));
    TILE_ENTRY(8);
    KTILE(sA1, sB1, STAGE(sA1, sB1, 2 * i + 3));
  }
  TILE_ENTRY(8);
  KTILE(sA0, sB0, (void)0);
  TILE_ENTRY(0);
  KTILE(sA1, sB1, (void)0);

  __syncthreads();

  const int part = tn >> 10;                  // 0=q 1=k 2=v
  const int cp = tn & 1023;
  const int bg = tm >> 8;
  const int hh = (cp >> 6) + wn;

  // ---- epilogue: per-wave LDS repack -> coalesced wide stores; ss fused ----
  u16* eb = (w == 0) ? sA0 : (w == 1) ? sA0 + 8192 : (w == 2) ? sA1 : (w == 3) ? sA1 + 8192
          : (w == 4) ? sB0 : (w == 5) ? sB0 + 8192 : (w == 6) ? sB1 : sB1 + 8192;
  float* fb = (float*)eb;                     // 16 x 68 f32 region per wave
  const int erow = lane >> 2, eseg = lane & 3;
  OUT* dstb;
  if constexpr (sizeof(OUT) == 2)
    dstb = C + (size_t)part * ((size_t)M_ * C_) + ((size_t)(bg * 16 + hh) * 256) * 64;
  else
    dstb = C + (size_t)tm * N + tn + wn * 64;
#pragma unroll
  for (int fm = 0; fm < 8; ++fm) {
#pragma unroll
    for (int fn = 0; fn < 4; ++fn)
#pragma unroll
      for (int r = 0; r < 4; ++r)
        fb[((lane >> 4) * 4 + r) * 68 + fn * 16 + (lane & 15)] = acc[fm][fn][r];
    asm volatile("s_waitcnt lgkmcnt(0)" ::: "memory");
    const float* src = &fb[erow * 68 + eseg * 16];
    f32x4 v0 = ((const f32x4*)src)[0], v1 = ((const f32x4*)src)[1];
    f32x4 v2 = ((const f32x4*)src)[2], v3 = ((const f32x4*)src)[3];
    if constexpr (sizeof(OUT) == 2) {
      if (part < 2) {                          // ss partial from repacked values
        float s = 0.f;
#pragma unroll
        for (int e = 0; e < 4; ++e)
          s += v0[e] * v0[e] + v1[e] * v1[e] + v2[e] * v2[e] + v3[e] * v3[e];
        s += __shfl_xor(s, 1, 64);
        s += __shfl_xor(s, 2, 64);
        if ((lane & 3) == 0) ssred[wn][wm * 128 + fm * 16 + erow] = s;
      }
    }
    OUT* dst;
    if constexpr (sizeof(OUT) == 2)
      dst = dstb + (size_t)(wm * 128 + fm * 16 + erow) * 64 + eseg * 16;
    else
      dst = dstb + (size_t)(wm * 128 + fm * 16 + erow) * N + eseg * 16;
    store16(dst, v0, v1, v2, v3);
  }
  if constexpr (sizeof(OUT) == 2) {
    if (part < 2) {
      __syncthreads();
      if (tid < 256) {
        float s = ssred[0][tid] + ssred[1][tid] + ssred[2][tid] + ssred[3][tid];
        (part == 0 ? ssq : ssk)[(size_t)(tm + tid) * 4 + (cp >> 8)] = s;
      }
    }
  }
#undef STAGE
#undef LDA_
#undef LDB_
#undef MM
#undef KTILE
#undef TILE_ENTRY
}

// ---------------- block-causal attention ----------------
// Round-7 structure (best: s[16] body, deep K-load ILP, no VGPR cap).
// ONE change: V staging via 8x8 in-register block transpose ->
// 8 ds_write_b128/thread instead of 64 ds_write_b16. Vt swizzle gains an
// extra ((d>>3)&7) term (applied identically on write and PV-read) to
// spread the wide writes across banks.
__global__ __launch_bounds__(256, 2) void attn_kernel(const u16* __restrict__ qkvblk,
                                                      const float* __restrict__ ssq,
                                                      const float* __restrict__ ssk,
                                                      const float* __restrict__ lnw,
                                                      u16* __restrict__ y) {
  const int bid = blockIdx.x;
  const int h = bid & 15;
  const int bg = bid >> 4;
  const size_t rowbase = (size_t)bg * 256;
  const u16* Qb = qkvblk + ((size_t)(bg * 16 + h) * 256) * 64;
  const u16* Kb = Qb + (size_t)M_ * C_;
  const u16* Vb = Qb + 2 * (size_t)M_ * C_;
  u16* Yb = y + ((size_t)(bg * 16 + h) * 256) * 64;

  __shared__ __align__(16) u16 Vt[64 * 256];      // 32KB [hd][k_tok], swizzled
  __shared__ __align__(16) u16 Ps[4][16 * 128];   // 16KB per-wave P-half / y repack
  __shared__ float kscl[256];
  __shared__ float lnsq[64];

  const int tid = threadIdx.x;
  const int lane = tid & 63;
  const int w = tid >> 6;
  const int g = lane >> 4;
  const int qi = lane & 15;

  // ---- prefetch Q fragments + ssq for this wave's 4 balanced q-tiles ----
  const int qts[4] = { w, 7 - w, 8 + w, 15 - w };
  bf16x8 qf0[4], qf1[4];
  f32x4 qv[4];
#pragma unroll
  for (int j = 0; j < 4; ++j) {
    const u16* qrow = Qb + (size_t)(qts[j] * 16 + qi) * 64 + g * 8;
    qf0[j] = *(const bf16x8*)(qrow);
    qf1[j] = *(const bf16x8*)(qrow + 32);
    qv[j] = ((const f32x4*)ssq)[rowbase + qts[j] * 16 + qi];
  }

  // ---- stage V: 8x8 block transpose in-register -> 8 wide LDS writes ----
  {
    const int r0 = (tid >> 3) * 8;        // 8 source rows per thread
    const int d0 = (tid & 7) * 8;         // 8 d-columns per thread
    bf16x8 vr[8];
#pragma unroll
    for (int rr = 0; rr < 8; ++rr)
      vr[rr] = *(const bf16x8*)(Vb + (size_t)(r0 + rr) * 64 + d0);
#pragma unroll
    for (int dd = 0; dd < 8; ++dd) {
      const int d = d0 + dd;
      u16x8 col;
#pragma unroll
      for (int rr = 0; rr < 8; ++rr) col[rr] = (u16)vr[rr][dd];
      const int sw = ((d & 7) ^ ((d >> 3) & 7)) << 4;
      *(u16x8*)((char*)Vt + d * 512 + ((2 * r0) ^ sw)) = col;
    }
    f32x4 kp = ((const f32x4*)ssk)[rowbase + tid];
    kscl[tid] = rsqrtf((kp[0] + kp[1] + kp[2] + kp[3]) * (1.0f / 1024.0f) + 1e-6f);
    if (tid < 64) { float a = lnw[h * 64 + tid]; lnsq[tid] = a * a; }
  }
  __syncthreads();

  // apply rms scale * lnw^2 to prefetched Q fragments
  {
    f32x4 wa0 = *(const f32x4*)&lnsq[g * 8],      wa1 = *(const f32x4*)&lnsq[g * 8 + 4];
    f32x4 wb0 = *(const f32x4*)&lnsq[32 + g * 8], wb1 = *(const f32x4*)&lnsq[32 + g * 8 + 4];
#pragma unroll
    for (int j = 0; j < 4; ++j) {
      const float qsc = rsqrtf((qv[j][0] + qv[j][1] + qv[j][2] + qv[j][3]) * (1.0f / 1024.0f) + 1e-6f);
#pragma unroll
      for (int e = 0; e < 4; ++e) {
        qf0[j][e]     = (short)f2bf(bf2f((u16)qf0[j][e]) * qsc * wa0[e]);
        qf0[j][4 + e] = (short)f2bf(bf2f((u16)qf0[j][4 + e]) * qsc * wa1[e]);
        qf1[j][e]     = (short)f2bf(bf2f((u16)qf1[j][e]) * qsc * wb0[e]);
        qf1[j][4 + e] = (short)f2bf(bf2f((u16)qf1[j][4 + e]) * qsc * wb1[e]);
      }
    }
  }

  char* pb = (char*)Ps[w];
  const int swq = (qi & 7) << 4;

  auto body = [&](int qt, bf16x8 q0, bf16x8 q1) {
    const int q = qt * 16 + qi;

    f32x4 s[16];
#pragma unroll
    for (int n = 0; n < 16; ++n) {
      if (n <= qt) {
        const u16* krow = Kb + (size_t)(n * 16 + qi) * 64 + g * 8;
        bf16x8 ka0 = *(const bf16x8*)(krow);
        bf16x8 ka1 = *(const bf16x8*)(krow + 32);
        f32x4 a = {0.f, 0.f, 0.f, 0.f};
        a = __builtin_amdgcn_mfma_f32_16x16x32_bf16(ka0, q0, a, 0, 0, 0);
        a = __builtin_amdgcn_mfma_f32_16x16x32_bf16(ka1, q1, a, 0, 0, 0);
        s[n] = a;
      }
    }

    float m = -3e38f;
#pragma unroll
    for (int n = 0; n < 16; ++n) if (n <= qt) {
      f32x4 k4 = *(const f32x4*)&kscl[n * 16 + g * 4];
#pragma unroll
      for (int r = 0; r < 4; ++r) {
        const int k_abs = n * 16 + g * 4 + r;
        float v = s[n][r] * 0.125f * k4[r];
        v = (k_abs <= q) ? v : -3e38f;
        s[n][r] = v;
        m = fmaxf(m, v);
      }
    }
    m = fmaxf(m, __shfl_xor(m, 16, 64));
    m = fmaxf(m, __shfl_xor(m, 32, 64));

    float sum = 0.f;
#pragma unroll
    for (int n = 0; n < 16; ++n) if (n <= qt) {
#pragma unroll
      for (int r = 0; r < 4; ++r) {
        float p = __expf(s[n][r] - m);
        s[n][r] = p;
        sum += p;
      }
    }
    sum += __shfl_xor(sum, 16, 64);
    sum += __shfl_xor(sum, 32, 64);

    f32x4 yacc[4];
#pragma unroll
    for (int dn = 0; dn < 4; ++dn) yacc[dn] = (f32x4){0.f, 0.f, 0.f, 0.f};
    const int nkf = qt / 2 + 1;

    // ---- P half 0 (k 0..127) + PV kf 0..3 ----
#pragma unroll
    for (int n = 0; n < 8; ++n) if (n <= qt) {
      u16x4 pk = { f2bf(s[n][0]), f2bf(s[n][1]), f2bf(s[n][2]), f2bf(s[n][3]) };
      *(u16x4*)(pb + qi * 256 + ((n * 32 + g * 8) ^ swq)) = pk;
    }
    if (!(qt & 1) && qt < 7) {      // zero-pad k-tile qt+1 (read by last 32-wide mfma)
      u16x4 z = {0, 0, 0, 0};
      *(u16x4*)(pb + qi * 256 + (((qt + 1) * 32 + g * 8) ^ swq)) = z;
    }
#pragma unroll
    for (int kf = 0; kf < 4; ++kf) if (kf < nkf) {
      bf16x8 pa = *(const bf16x8*)(pb + qi * 256 + ((kf * 64 + g * 16) ^ swq));
#pragma unroll
      for (int dn = 0; dn < 4; ++dn) {
        const int d = dn * 16 + qi;
        const int swv = ((d & 7) ^ ((d >> 3) & 7)) << 4;
        bf16x8 vb = *(const bf16x8*)((const char*)Vt + d * 512 + ((kf * 64 + g * 16) ^ swv));
        yacc[dn] = __builtin_amdgcn_mfma_f32_16x16x32_bf16(pa, vb, yacc[dn], 0, 0, 0);
      }
    }

    // ---- P half 1 (k 128..255) + PV kf 4..7 (per-wave private; DS in-order) ----
    if (qt >= 8) {
#pragma unroll
      for (int n = 8; n < 16; ++n) if (n <= qt) {
        u16x4 pk = { f2bf(s[n][0]), f2bf(s[n][1]), f2bf(s[n][2]), f2bf(s[n][3]) };
        *(u16x4*)(pb + qi * 256 + (((n - 8) * 32 + g * 8) ^ swq)) = pk;
      }
      if (!(qt & 1)) {
        u16x4 z = {0, 0, 0, 0};
        *(u16x4*)(pb + qi * 256 + (((qt - 7) * 32 + g * 8) ^ swq)) = z;
      }
#pragma unroll
      for (int kf = 4; kf < 8; ++kf) if (kf < nkf) {
        bf16x8 pa = *(const bf16x8*)(pb + qi * 256 + (((kf - 4) * 64 + g * 16) ^ swq));
#pragma unroll
        for (int dn = 0; dn < 4; ++dn) {
          const int d = dn * 16 + qi;
          const int swv = ((d & 7) ^ ((d >> 3) & 7)) << 4;
          bf16x8 vb = *(const bf16x8*)((const char*)Vt + d * 512 + ((kf * 64 + g * 16) ^ swv));
          yacc[dn] = __builtin_amdgcn_mfma_f32_16x16x32_bf16(pa, vb, yacc[dn], 0, 0, 0);
        }
      }
    }

    // ---- y repack through pb (private) -> fully contiguous stores ----
#pragma unroll
    for (int r = 0; r < 4; ++r) {
      const float inv = 1.0f / __shfl(sum, g * 4 + r, 64);
      const int row = g * 4 + r;
#pragma unroll
      for (int dn = 0; dn < 4; ++dn)
        *(u16*)(pb + row * 128 + ((dn * 32 + qi * 2) ^ ((row & 7) << 4))) =
            f2bf(yacc[dn][r] * inv);
    }
    // two stores: each covers 8 rows x 128B = 1KB contiguous across the wave
#pragma unroll
    for (int half = 0; half < 2; ++half) {
      const int row = half * 8 + (lane >> 3);
      const int c16 = lane & 7;
      u16x8 v = *(const u16x8*)(pb + row * 128 + ((c16 * 16) ^ ((row & 7) << 4)));
      *(u16x8*)(Yb + (size_t)(qt * 16 + row) * 64 + c16 * 8) = v;
    }
  };

  body(qts[0], qf0[0], qf1[0]);
  body(qts[1], qf0[1], qf1[1]);
  body(qts[2], qf0[2], qf1[2]);
  body(qts[3], qf0[3], qf1[3]);
}

// ---------------- launch ----------------
extern "C" void kernel_launch(void* const* d_in, const int* in_sizes, int n_in,
                              void* d_out, int out_size, void* d_ws, size_t ws_size,
                              hipStream_t stream) {
  const float* x      = (const float*)d_in[0];   // [16384][1024]
  const float* w_qkv  = (const float*)d_in[1];   // [1024][3072]
  const float* ln_w   = (const float*)d_in[2];   // [1024]
  const float* w_proj = (const float*)d_in[3];   // [1024][1024]
  float* out = (float*)d_out;                    // [16384][1024] fp32

  u16* xb     = (u16*)d_ws;                          // 16384*1024
  u16* wqkvT  = xb + (size_t)M_ * C_;                // 3072*1024 (transposed)
  u16* wprojT = wqkvT + (size_t)N1_ * C_;            // 1024*1024 (transposed)
  u16* qkvblk = wprojT + (size_t)C_ * C_;            // 3 * 16384*1024 head-blocked
  u16* yb     = qkvblk + 3 * (size_t)M_ * C_;        // 16384*1024 head-blocked
  float* ssq  = (float*)(yb + (size_t)M_ * C_);      // 16384*4 f32
  float* ssk  = ssq + (size_t)M_ * 4;                // 16384*4 f32

  cast_f32_bf16<<<(M_ * C_) / 1024, 256, 0, stream>>>(x, xb);
  transpose_cast<<<dim3(N1_ / 64, C_ / 64), 256, 0, stream>>>(w_qkv, wqkvT, C_, N1_);
  transpose_cast<<<dim3(C_ / 64, C_ / 64), 256, 0, stream>>>(w_proj, wprojT, C_, C_);

  gemm256<u16, false><<<(M_ / 256) * (N1_ / 256), 512, 0, stream>>>(
      xb, wqkvT, qkvblk, M_, N1_, N1_ / 256, ssq, ssk);
  attn_kernel<<<64 * 16, 256, 0, stream>>>(qkvblk, ssq, ssk, ln_w, yb);
  gemm256<float, true><<<(M_ / 256) * (C_ / 256), 512, 0, stream>>>(
      yb, wprojT, out, M_, C_, C_ / 256, nullptr, nullptr);
}

// Round 10
// 241.354 us; speedup vs baseline: 1.0570x; 1.0001x over previous
//
#include <hip/hip_runtime.h>

typedef __attribute__((ext_vector_type(4))) float f32x4;
typedef __attribute__((ext_vector_type(8))) short bf16x8;
typedef __attribute__((ext_vector_type(4))) unsigned short u16x4;
typedef __attribute__((ext_vector_type(8))) unsigned short u16x8;
typedef unsigned short u16;
typedef unsigned int u32;

// B=4 T=4096 C=1024 H=16 LS=256
#define M_  16384   // B*T
#define C_  1024
#define N1_ 3072    // 3C

__device__ __forceinline__ float bf2f(u16 u) {
  union { u32 i; float f; } v; v.i = ((u32)u) << 16; return v.f;
}
__device__ __forceinline__ u16 f2bf(float f) {
  union { float f; u32 i; } v; v.f = f;
  u32 r = v.i + 0x7fffu + ((v.i >> 16) & 1u);   // RN-even
  return (u16)(r >> 16);
}

__device__ __forceinline__ void gload16(const void* g, void* l) {
  __builtin_amdgcn_global_load_lds(
      (const __attribute__((address_space(1))) u32*)g,
      (__attribute__((address_space(3))) u32*)l, 16, 0, 0);
}

// ---------------- fused prologue: cast x + transpose both weight mats ----------------
// blocks [0,16384): cast x -> xb ; [16384,17152): w_qkv^T ; [17152,17408): w_proj^T
__global__ __launch_bounds__(256) void prologue_kernel(const float* __restrict__ x,
                                                       u16* __restrict__ xb,
                                                       const float* __restrict__ w_qkv,
                                                       u16* __restrict__ wqkvT,
                                                       const float* __restrict__ w_proj,
                                                       u16* __restrict__ wprojT) {
  __shared__ u16 tile[64][65];
  const int b = blockIdx.x;
  const int tid = threadIdx.x;
  if (b < 16384) {
    size_t i = (size_t)b * 256 + tid;
    f32x4 v = ((const f32x4*)x)[i];
    u16x4 o = { f2bf(v[0]), f2bf(v[1]), f2bf(v[2]), f2bf(v[3]) };
    ((u16x4*)xb)[i] = o;
    return;
  }
  const float* in; u16* out; int K, N, n0, k0;
  if (b < 16384 + 768) {
    const int idx = b - 16384;                 // 48 x 16 tiles
    in = w_qkv; out = wqkvT; K = 1024; N = 3072;
    n0 = (idx % 48) * 64; k0 = (idx / 48) * 64;
  } else {
    const int idx = b - 17152;                 // 16 x 16 tiles
    in = w_proj; out = wprojT; K = 1024; N = 1024;
    n0 = (idx % 16) * 64; k0 = (idx / 16) * 64;
  }
  const int nn = tid & 63, kk = tid >> 6;
#pragma unroll
  for (int r = 0; r < 16; ++r)
    tile[kk * 16 + r][nn] = f2bf(in[(size_t)(k0 + kk * 16 + r) * N + n0 + nn]);
  __syncthreads();
  const int kc = tid & 15, nl = tid >> 4;
#pragma unroll
  for (int p = 0; p < 4; ++p) {
    const int n = p * 16 + nl;
    u16x4 v = { tile[kc * 4 + 0][n], tile[kc * 4 + 1][n],
                tile[kc * 4 + 2][n], tile[kc * 4 + 3][n] };
    *(u16x4*)(out + (size_t)(n0 + n) * K + k0 + kc * 4) = v;
  }
}

// ---------------- GEMM 256x256, BK=64, static-parity double buffer ----------------
__device__ __forceinline__ void store16(float* dst, f32x4 v0, f32x4 v1, f32x4 v2, f32x4 v3) {
  ((f32x4*)dst)[0] = v0; ((f32x4*)dst)[1] = v1; ((f32x4*)dst)[2] = v2; ((f32x4*)dst)[3] = v3;
}
__device__ __forceinline__ void store16(u16* dst, f32x4 v0, f32x4 v1, f32x4 v2, f32x4 v3) {
  u16x8 o0 = { f2bf(v0[0]), f2bf(v0[1]), f2bf(v0[2]), f2bf(v0[3]),
               f2bf(v1[0]), f2bf(v1[1]), f2bf(v1[2]), f2bf(v1[3]) };
  u16x8 o1 = { f2bf(v2[0]), f2bf(v2[1]), f2bf(v2[2]), f2bf(v2[3]),
               f2bf(v3[0]), f2bf(v3[1]), f2bf(v3[2]), f2bf(v3[3]) };
  *(u16x8*)dst = o0; *(u16x8*)(dst + 8) = o1;
}

// C = A * BT^T, bf16 in, fp32 acc. 512 thr (8 waves 2Mx4N). K=1024.
// Staging is split: B-loads issue after P2's closing barrier (every wave's
// B-slice reads finish in P1+P2), A-loads at P4 (after P3's closing barrier)
// -- two issue points per K-tile instead of one (m196 fine-interleave lever).
template <typename OUT, bool AHB>
__global__ __launch_bounds__(512, 2) void gemm256(const u16* __restrict__ A,
                                                  const u16* __restrict__ BT,
                                                  OUT* __restrict__ C,
                                                  int M, int N, int ntn,
                                                  float* __restrict__ ssq,
                                                  float* __restrict__ ssk) {
  constexpr int ARS   = AHB ? 64 : 1024;     // A row stride (elements)
  constexpr int ASTEP = AHB ? 16384 : 64;    // A K-tile step (elements)
  __shared__ __align__(16) u16 sA0[256 * 64], sA1[256 * 64];
  __shared__ __align__(16) u16 sB0[256 * 64], sB1[256 * 64];
  __shared__ float ssred[4][256];
  const int tid = threadIdx.x, lane = tid & 63, w = tid >> 6;
  const int wm = w >> 2, wn = w & 3;

  int bid = blockIdx.x;
  const int cpx = gridDim.x >> 3;              // grid % 8 == 0 for all our launches
  bid = (bid & 7) * cpx + (bid >> 3);          // XCD swizzle (T1)
  const int tm = (bid / ntn) << 8, tn = (bid % ntn) << 8;

  const u16* srcA[4]; const u16* srcB[4]; int ldsOff[4];
#pragma unroll
  for (int l = 0; l < 4; ++l) {
    const int g = l * 512 + tid;
    const int row = g >> 3, c = g & 7;
    srcA[l] = A + (size_t)tm * 1024 + (size_t)row * ARS + ((c ^ (row & 7)) << 3);
    srcB[l] = BT + (size_t)(tn + row) * 1024 + ((c ^ (row & 7)) << 3);
    ldsOff[l] = g << 4;
  }

#define STAGE(sa, sb, kt) do {                                                 \
    _Pragma("unroll") for (int _l = 0; _l < 4; ++_l) {                         \
      gload16(srcA[_l] + (kt) * ASTEP, (char*)(sa) + ldsOff[_l]);              \
      gload16(srcB[_l] + (kt) * 64, (char*)(sb) + ldsOff[_l]); } } while (0)

  const int swz = (lane & 7) << 4;
  const int r16 = lane & 15;
  const int kb = (lane >> 4) << 4;
#define LDA_(sa, fm, ks) (*(const bf16x8*)((const char*)(sa) + \
    (wm * 128 + (fm) * 16 + r16) * 128 + ((((ks) << 6) | kb) ^ swz)))
#define LDB_(sb, fn, ks) (*(const bf16x8*)((const char*)(sb) + \
    (wn * 64 + (fn) * 16 + r16) * 128 + ((((ks) << 6) | kb) ^ swz)))

  f32x4 acc[8][4];
#pragma unroll
  for (int i = 0; i < 8; ++i)
#pragma unroll
    for (int j = 0; j < 4; ++j) acc[i][j] = (f32x4){0.f, 0.f, 0.f, 0.f};

#define MM(i, j, a_, b_) acc[i][j] = __builtin_amdgcn_mfma_f32_16x16x32_bf16(a_, b_, acc[i][j], 0, 0, 0)

// One K-tile = 4 phases. DOSTG is a literal 0/1: when 1, B-prefetch (4 loads,
// tile kt) issues after P2's closing barrier; A-prefetch (4 loads) at P4.
#define KTILE(sa, sb, kt, DOSTG) do {                                          \
  bf16x8 ka[4][2], kb0[2][2], kb1[2][2];                                       \
  _Pragma("unroll") for (int fm = 0; fm < 4; ++fm) {                           \
    ka[fm][0] = LDA_(sa, fm, 0); ka[fm][1] = LDA_(sa, fm, 1); }                \
  _Pragma("unroll") for (int fn = 0; fn < 2; ++fn) {                           \
    kb0[fn][0] = LDB_(sb, fn, 0); kb0[fn][1] = LDB_(sb, fn, 1); }              \
  __builtin_amdgcn_s_barrier();                                                \
  __builtin_amdgcn_s_setprio(1);                                               \
  _Pragma("unroll") for (int fm = 0; fm < 4; ++fm)                             \
    _Pragma("unroll") for (int fn = 0; fn < 2; ++fn) {                         \
      MM(fm, fn, ka[fm][0], kb0[fn][0]); MM(fm, fn, ka[fm][1], kb0[fn][1]); }  \
  __builtin_amdgcn_s_setprio(0);                                               \
  __builtin_amdgcn_s_barrier();                                                \
  _Pragma("unroll") for (int fn = 0; fn < 2; ++fn) {                           \
    kb1[fn][0] = LDB_(sb, 2 + fn, 0); kb1[fn][1] = LDB_(sb, 2 + fn, 1); }      \
  __builtin_amdgcn_s_barrier();                                                \
  __builtin_amdgcn_s_setprio(1);                                               \
  _Pragma("unroll") for (int fm = 0; fm < 4; ++fm)                             \
    _Pragma("unroll") for (int fn = 0; fn < 2; ++fn) {                         \
      MM(fm, 2 + fn, ka[fm][0], kb1[fn][0]); MM(fm, 2 + fn, ka[fm][1], kb1[fn][1]); } \
  __builtin_amdgcn_s_setprio(0);                                               \
  __builtin_amdgcn_s_barrier();                                                \
  if (DOSTG) {                               /* B fully read by all waves */   \
    __builtin_amdgcn_sched_barrier(0);                                         \
    _Pragma("unroll") for (int _l = 0; _l < 4; ++_l)                           \
      gload16(srcB[_l] + (kt) * 64, (char*)(sb) + ldsOff[_l]);                 \
  }                                                                            \
  _Pragma("unroll") for (int fm = 0; fm < 4; ++fm) {                           \
    ka[fm][0] = LDA_(sa, 4 + fm, 0); ka[fm][1] = LDA_(sa, 4 + fm, 1); }        \
  __builtin_amdgcn_s_barrier();                                                \
  __builtin_amdgcn_s_setprio(1);                                               \
  _Pragma("unroll") for (int fm = 0; fm < 4; ++fm)                             \
    _Pragma("unroll") for (int fn = 0; fn < 2; ++fn) {                         \
      MM(4 + fm, 2 + fn, ka[fm][0], kb1[fn][0]); MM(4 + fm, 2 + fn, ka[fm][1], kb1[fn][1]); } \
  __builtin_amdgcn_s_setprio(0);                                               \
  __builtin_amdgcn_s_barrier();                                                \
  __builtin_amdgcn_sched_barrier(0);                                           \
  if (DOSTG) {                               /* A fully read by all waves */   \
    _Pragma("unroll") for (int _l = 0; _l < 4; ++_l)                           \
      gload16(srcA[_l] + (kt) * ASTEP, (char*)(sa) + ldsOff[_l]);              \
  }                                                                            \
  __builtin_amdgcn_s_setprio(1);                                               \
  _Pragma("unroll") for (int fm = 0; fm < 4; ++fm)                             \
    _Pragma("unroll") for (int fn = 0; fn < 2; ++fn) {                         \
      MM(4 + fm, fn, ka[fm][0], kb0[fn][0]); MM(4 + fm, fn, ka[fm][1], kb0[fn][1]); } \
  __builtin_amdgcn_s_setprio(0);                                               \
} while (0)

#define TILE_ENTRY(vm) do { __builtin_amdgcn_sched_barrier(0);                 \
    asm volatile("s_waitcnt vmcnt(" #vm ")");                                  \
    __builtin_amdgcn_sched_barrier(0);                                         \
    __builtin_amdgcn_s_barrier();                                              \
    __builtin_amdgcn_sched_barrier(0); } while (0)

  STAGE(sA0, sB0, 0);
  STAGE(sA1, sB1, 1);

#pragma unroll 1
  for (int i = 0; i < 7; ++i) {
    TILE_ENTRY(8);
    KTILE(sA0, sB0, 2 * i + 2, 1);
    TILE_ENTRY(8);
    KTILE(sA1, sB1, 2 * i + 3, 1);
  }
  TILE_ENTRY(8);
  KTILE(sA0, sB0, 0, 0);
  TILE_ENTRY(0);
  KTILE(sA1, sB1, 0, 0);

  __syncthreads();

  const int part = tn >> 10;                  // 0=q 1=k 2=v
  const int cp = tn & 1023;
  const int bg = tm >> 8;
  const int hh = (cp >> 6) + wn;

  // ---- epilogue: per-wave LDS repack -> coalesced wide stores; ss fused ----
  u16* eb = (w == 0) ? sA0 : (w == 1) ? sA0 + 8192 : (w == 2) ? sA1 : (w == 3) ? sA1 + 8192
          : (w == 4) ? sB0 : (w == 5) ? sB0 + 8192 : (w == 6) ? sB1 : sB1 + 8192;
  float* fb = (float*)eb;                     // 16 x 68 f32 region per wave
  const int erow = lane >> 2, eseg = lane & 3;
  OUT* dstb;
  if constexpr (sizeof(OUT) == 2)
    dstb = C + (size_t)part * ((size_t)M_ * C_) + ((size_t)(bg * 16 + hh) * 256) * 64;
  else
    dstb = C + (size_t)tm * N + tn + wn * 64;
#pragma unroll
  for (int fm = 0; fm < 8; ++fm) {
#pragma unroll
    for (int fn = 0; fn < 4; ++fn)
#pragma unroll
      for (int r = 0; r < 4; ++r)
        fb[((lane >> 4) * 4 + r) * 68 + fn * 16 + (lane & 15)] = acc[fm][fn][r];
    asm volatile("s_waitcnt lgkmcnt(0)" ::: "memory");
    const float* src = &fb[erow * 68 + eseg * 16];
    f32x4 v0 = ((const f32x4*)src)[0], v1 = ((const f32x4*)src)[1];
    f32x4 v2 = ((const f32x4*)src)[2], v3 = ((const f32x4*)src)[3];
    if constexpr (sizeof(OUT) == 2) {
      if (part < 2) {                          // ss partial from repacked values
        float s = 0.f;
#pragma unroll
        for (int e = 0; e < 4; ++e)
          s += v0[e] * v0[e] + v1[e] * v1[e] + v2[e] * v2[e] + v3[e] * v3[e];
        s += __shfl_xor(s, 1, 64);
        s += __shfl_xor(s, 2, 64);
        if ((lane & 3) == 0) ssred[wn][wm * 128 + fm * 16 + erow] = s;
      }
    }
    OUT* dst;
    if constexpr (sizeof(OUT) == 2)
      dst = dstb + (size_t)(wm * 128 + fm * 16 + erow) * 64 + eseg * 16;
    else
      dst = dstb + (size_t)(wm * 128 + fm * 16 + erow) * N + eseg * 16;
    store16(dst, v0, v1, v2, v3);
  }
  if constexpr (sizeof(OUT) == 2) {
    if (part < 2) {
      __syncthreads();
      if (tid < 256) {
        float s = ssred[0][tid] + ssred[1][tid] + ssred[2][tid] + ssred[3][tid];
        (part == 0 ? ssq : ssk)[(size_t)(tm + tid) * 4 + (cp >> 8)] = s;
      }
    }
  }
#undef STAGE
#undef LDA_
#undef LDB_
#undef MM
#undef KTILE
#undef TILE_ENTRY
}

// ---------------- block-causal attention (round-9 structure, frozen) ----------------
__global__ __launch_bounds__(256, 2) void attn_kernel(const u16* __restrict__ qkvblk,
                                                      const float* __restrict__ ssq,
                                                      const float* __restrict__ ssk,
                                                      const float* __restrict__ lnw,
                                                      u16* __restrict__ y) {
  const int bid = blockIdx.x;
  const int h = bid & 15;
  const int bg = bid >> 4;
  const size_t rowbase = (size_t)bg * 256;
  const u16* Qb = qkvblk + ((size_t)(bg * 16 + h) * 256) * 64;
  const u16* Kb = Qb + (size_t)M_ * C_;
  const u16* Vb = Qb + 2 * (size_t)M_ * C_;
  u16* Yb = y + ((size_t)(bg * 16 + h) * 256) * 64;

  __shared__ __align__(16) u16 Vt[64 * 256];      // 32KB [hd][k_tok], swizzled
  __shared__ __align__(16) u16 Ps[4][16 * 128];   // 16KB per-wave P-half / y repack
  __shared__ float kscl[256];
  __shared__ float lnsq[64];

  const int tid = threadIdx.x;
  const int lane = tid & 63;
  const int w = tid >> 6;
  const int g = lane >> 4;
  const int qi = lane & 15;

  // ---- prefetch Q fragments + ssq for this wave's 4 balanced q-tiles ----
  const int qts[4] = { w, 7 - w, 8 + w, 15 - w };
  bf16x8 qf0[4], qf1[4];
  f32x4 qv[4];
#pragma unroll
  for (int j = 0; j < 4; ++j) {
    const u16* qrow = Qb + (size_t)(qts[j] * 16 + qi) * 64 + g * 8;
    qf0[j] = *(const bf16x8*)(qrow);
    qf1[j] = *(const bf16x8*)(qrow + 32);
    qv[j] = ((const f32x4*)ssq)[rowbase + qts[j] * 16 + qi];
  }

  // ---- stage V: 8x8 block transpose in-register -> 8 wide LDS writes ----
  {
    const int r0 = (tid >> 3) * 8;        // 8 source rows per thread
    const int d0 = (tid & 7) * 8;         // 8 d-columns per thread
    bf16x8 vr[8];
#pragma unroll
    for (int rr = 0; rr < 8; ++rr)
      vr[rr] = *(const bf16x8*)(Vb + (size_t)(r0 + rr) * 64 + d0);
#pragma unroll
    for (int dd = 0; dd < 8; ++dd) {
      const int d = d0 + dd;
      u16x8 col;
#pragma unroll
      for (int rr = 0; rr < 8; ++rr) col[rr] = (u16)vr[rr][dd];
      const int sw = ((d & 7) ^ ((d >> 3) & 7)) << 4;
      *(u16x8*)((char*)Vt + d * 512 + ((2 * r0) ^ sw)) = col;
    }
    f32x4 kp = ((const f32x4*)ssk)[rowbase + tid];
    kscl[tid] = rsqrtf((kp[0] + kp[1] + kp[2] + kp[3]) * (1.0f / 1024.0f) + 1e-6f);
    if (tid < 64) { float a = lnw[h * 64 + tid]; lnsq[tid] = a * a; }
  }
  __syncthreads();

  // apply rms scale * lnw^2 to prefetched Q fragments
  {
    f32x4 wa0 = *(const f32x4*)&lnsq[g * 8],      wa1 = *(const f32x4*)&lnsq[g * 8 + 4];
    f32x4 wb0 = *(const f32x4*)&lnsq[32 + g * 8], wb1 = *(const f32x4*)&lnsq[32 + g * 8 + 4];
#pragma unroll
    for (int j = 0; j < 4; ++j) {
      const float qsc = rsqrtf((qv[j][0] + qv[j][1] + qv[j][2] + qv[j][3]) * (1.0f / 1024.0f) + 1e-6f);
#pragma unroll
      for (int e = 0; e < 4; ++e) {
        qf0[j][e]     = (short)f2bf(bf2f((u16)qf0[j][e]) * qsc * wa0[e]);
        qf0[j][4 + e] = (short)f2bf(bf2f((u16)qf0[j][4 + e]) * qsc * wa1[e]);
        qf1[j][e]     = (short)f2bf(bf2f((u16)qf1[j][e]) * qsc * wb0[e]);
        qf1[j][4 + e] = (short)f2bf(bf2f((u16)qf1[j][4 + e]) * qsc * wb1[e]);
      }
    }
  }

  char* pb = (char*)Ps[w];
  const int swq = (qi & 7) << 4;

  auto body = [&](int qt, bf16x8 q0, bf16x8 q1) {
    const int q = qt * 16 + qi;

    f32x4 s[16];
#pragma unroll
    for (int n = 0; n < 16; ++n) {
      if (n <= qt) {
        const u16* krow = Kb + (size_t)(n * 16 + qi) * 64 + g * 8;
        bf16x8 ka0 = *(const bf16x8*)(krow);
        bf16x8 ka1 = *(const bf16x8*)(krow + 32);
        f32x4 a = {0.f, 0.f, 0.f, 0.f};
        a = __builtin_amdgcn_mfma_f32_16x16x32_bf16(ka0, q0, a, 0, 0, 0);
        a = __builtin_amdgcn_mfma_f32_16x16x32_bf16(ka1, q1, a, 0, 0, 0);
        s[n] = a;
      }
    }

    float m = -3e38f;
#pragma unroll
    for (int n = 0; n < 16; ++n) if (n <= qt) {
      f32x4 k4 = *(const f32x4*)&kscl[n * 16 + g * 4];
#pragma unroll
      for (int r = 0; r < 4; ++r) {
        const int k_abs = n * 16 + g * 4 + r;
        float v = s[n][r] * 0.125f * k4[r];
        v = (k_abs <= q) ? v : -3e38f;
        s[n][r] = v;
        m = fmaxf(m, v);
      }
    }
    m = fmaxf(m, __shfl_xor(m, 16, 64));
    m = fmaxf(m, __shfl_xor(m, 32, 64));

    float sum = 0.f;
#pragma unroll
    for (int n = 0; n < 16; ++n) if (n <= qt) {
#pragma unroll
      for (int r = 0; r < 4; ++r) {
        float p = __expf(s[n][r] - m);
        s[n][r] = p;
        sum += p;
      }
    }
    sum += __shfl_xor(sum, 16, 64);
    sum += __shfl_xor(sum, 32, 64);

    f32x4 yacc[4];
#pragma unroll
    for (int dn = 0; dn < 4; ++dn) yacc[dn] = (f32x4){0.f, 0.f, 0.f, 0.f};
    const int nkf = qt / 2 + 1;

    // ---- P half 0 (k 0..127) + PV kf 0..3 ----
#pragma unroll
    for (int n = 0; n < 8; ++n) if (n <= qt) {
      u16x4 pk = { f2bf(s[n][0]), f2bf(s[n][1]), f2bf(s[n][2]), f2bf(s[n][3]) };
      *(u16x4*)(pb + qi * 256 + ((n * 32 + g * 8) ^ swq)) = pk;
    }
    if (!(qt & 1) && qt < 7) {      // zero-pad k-tile qt+1 (read by last 32-wide mfma)
      u16x4 z = {0, 0, 0, 0};
      *(u16x4*)(pb + qi * 256 + (((qt + 1) * 32 + g * 8) ^ swq)) = z;
    }
#pragma unroll
    for (int kf = 0; kf < 4; ++kf) if (kf < nkf) {
      bf16x8 pa = *(const bf16x8*)(pb + qi * 256 + ((kf * 64 + g * 16) ^ swq));
#pragma unroll
      for (int dn = 0; dn < 4; ++dn) {
        const int d = dn * 16 + qi;
        const int swv = ((d & 7) ^ ((d >> 3) & 7)) << 4;
        bf16x8 vb = *(const bf16x8*)((const char*)Vt + d * 512 + ((kf * 64 + g * 16) ^ swv));
        yacc[dn] = __builtin_amdgcn_mfma_f32_16x16x32_bf16(pa, vb, yacc[dn], 0, 0, 0);
      }
    }

    // ---- P half 1 (k 128..255) + PV kf 4..7 (per-wave private; DS in-order) ----
    if (qt >= 8) {
#pragma unroll
      for (int n = 8; n < 16; ++n) if (n <= qt) {
        u16x4 pk = { f2bf(s[n][0]), f2bf(s[n][1]), f2bf(s[n][2]), f2bf(s[n][3]) };
        *(u16x4*)(pb + qi * 256 + (((n - 8) * 32 + g * 8) ^ swq)) = pk;
      }
      if (!(qt & 1)) {
        u16x4 z = {0, 0, 0, 0};
        *(u16x4*)(pb + qi * 256 + (((qt - 7) * 32 + g * 8) ^ swq)) = z;
      }
#pragma unroll
      for (int kf = 4; kf < 8; ++kf) if (kf < nkf) {
        bf16x8 pa = *(const bf16x8*)(pb + qi * 256 + (((kf - 4) * 64 + g * 16) ^ swq));
#pragma unroll
        for (int dn = 0; dn < 4; ++dn) {
          const int d = dn * 16 + qi;
          const int swv = ((d & 7) ^ ((d >> 3) & 7)) << 4;
          bf16x8 vb = *(const bf16x8*)((const char*)Vt + d * 512 + ((kf * 64 + g * 16) ^ swv));
          yacc[dn] = __builtin_amdgcn_mfma_f32_16x16x32_bf16(pa, vb, yacc[dn], 0, 0, 0);
        }
      }
    }

    // ---- y repack through pb (private) -> fully contiguous stores ----
#pragma unroll
    for (int r = 0; r < 4; ++r) {
      const float inv = 1.0f / __shfl(sum, g * 4 + r, 64);
      const int row = g * 4 + r;
#pragma unroll
      for (int dn = 0; dn < 4; ++dn)
        *(u16*)(pb + row * 128 + ((dn * 32 + qi * 2) ^ ((row & 7) << 4))) =
            f2bf(yacc[dn][r] * inv);
    }
#pragma unroll
    for (int half = 0; half < 2; ++half) {
      const int row = half * 8 + (lane >> 3);
      const int c16 = lane & 7;
      u16x8 v = *(const u16x8*)(pb + row * 128 + ((c16 * 16) ^ ((row & 7) << 4)));
      *(u16x8*)(Yb + (size_t)(qt * 16 + row) * 64 + c16 * 8) = v;
    }
  };

  body(qts[0], qf0[0], qf1[0]);
  body(qts[1], qf0[1], qf1[1]);
  body(qts[2], qf0[2], qf1[2]);
  body(qts[3], qf0[3], qf1[3]);
}

// ---------------- launch ----------------
extern "C" void kernel_launch(void* const* d_in, const int* in_sizes, int n_in,
                              void* d_out, int out_size, void* d_ws, size_t ws_size,
                              hipStream_t stream) {
  const float* x      = (const float*)d_in[0];   // [16384][1024]
  const float* w_qkv  = (const float*)d_in[1];   // [1024][3072]
  const float* ln_w   = (const float*)d_in[2];   // [1024]
  const float* w_proj = (const float*)d_in[3];   // [1024][1024]
  float* out = (float*)d_out;                    // [16384][1024] fp32

  u16* xb     = (u16*)d_ws;                          // 16384*1024
  u16* wqkvT  = xb + (size_t)M_ * C_;                // 3072*1024 (transposed)
  u16* wprojT = wqkvT + (size_t)N1_ * C_;            // 1024*1024 (transposed)
  u16* qkvblk = wprojT + (size_t)C_ * C_;            // 3 * 16384*1024 head-blocked
  u16* yb     = qkvblk + 3 * (size_t)M_ * C_;        // 16384*1024 head-blocked
  float* ssq  = (float*)(yb + (size_t)M_ * C_);      // 16384*4 f32
  float* ssk  = ssq + (size_t)M_ * 4;                // 16384*4 f32

  prologue_kernel<<<16384 + 768 + 256, 256, 0, stream>>>(x, xb, w_qkv, wqkvT, w_proj, wprojT);

  gemm256<u16, false><<<(M_ / 256) * (N1_ / 256), 512, 0, stream>>>(
      xb, wqkvT, qkvblk, M_, N1_, N1_ / 256, ssq, ssk);
  attn_kernel<<<64 * 16, 256, 0, stream>>>(qkvblk, ssq, ssk, ln_w, yb);
  gemm256<float, true><<<(M_ / 256) * (C_ / 256), 512, 0, stream>>>(
      yb, wprojT, out, M_, C_, C_ / 256, nullptr, nullptr);
}

// Round 11
// 239.234 us; speedup vs baseline: 1.0664x; 1.0089x over previous
//
#include <hip/hip_runtime.h>

typedef __attribute__((ext_vector_type(4))) float f32x4;
typedef __attribute__((ext_vector_type(8))) short bf16x8;
typedef __attribute__((ext_vector_type(4))) unsigned short u16x4;
typedef __attribute__((ext_vector_type(8))) unsigned short u16x8;
typedef unsigned short u16;
typedef unsigned int u32;

// B=4 T=4096 C=1024 H=16 LS=256
#define M_  16384   // B*T
#define C_  1024
#define N1_ 3072    // 3C

__device__ __forceinline__ float bf2f(u16 u) {
  union { u32 i; float f; } v; v.i = ((u32)u) << 16; return v.f;
}
__device__ __forceinline__ u16 f2bf(float f) {
  union { float f; u32 i; } v; v.f = f;
  u32 r = v.i + 0x7fffu + ((v.i >> 16) & 1u);   // RN-even
  return (u16)(r >> 16);
}

__device__ __forceinline__ void gload16(const void* g, void* l) {
  __builtin_amdgcn_global_load_lds(
      (const __attribute__((address_space(1))) u32*)g,
      (__attribute__((address_space(3))) u32*)l, 16, 0, 0);
}

// ---------------- fused prologue: cast x + transpose both weight mats ----------------
// blocks [0,16384): cast x -> xb ; [16384,17152): w_qkv^T ; [17152,17408): w_proj^T
__global__ __launch_bounds__(256) void prologue_kernel(const float* __restrict__ x,
                                                       u16* __restrict__ xb,
                                                       const float* __restrict__ w_qkv,
                                                       u16* __restrict__ wqkvT,
                                                       const float* __restrict__ w_proj,
                                                       u16* __restrict__ wprojT) {
  __shared__ u16 tile[64][65];
  const int b = blockIdx.x;
  const int tid = threadIdx.x;
  if (b < 16384) {
    size_t i = (size_t)b * 256 + tid;
    f32x4 v = ((const f32x4*)x)[i];
    u16x4 o = { f2bf(v[0]), f2bf(v[1]), f2bf(v[2]), f2bf(v[3]) };
    ((u16x4*)xb)[i] = o;
    return;
  }
  const float* in; u16* out; int K, N, n0, k0;
  if (b < 16384 + 768) {
    const int idx = b - 16384;                 // 48 x 16 tiles
    in = w_qkv; out = wqkvT; K = 1024; N = 3072;
    n0 = (idx % 48) * 64; k0 = (idx / 48) * 64;
  } else {
    const int idx = b - 17152;                 // 16 x 16 tiles
    in = w_proj; out = wprojT; K = 1024; N = 1024;
    n0 = (idx % 16) * 64; k0 = (idx / 16) * 64;
  }
  const int nn = tid & 63, kk = tid >> 6;
#pragma unroll
  for (int r = 0; r < 16; ++r)
    tile[kk * 16 + r][nn] = f2bf(in[(size_t)(k0 + kk * 16 + r) * N + n0 + nn]);
  __syncthreads();
  const int kc = tid & 15, nl = tid >> 4;
#pragma unroll
  for (int p = 0; p < 4; ++p) {
    const int n = p * 16 + nl;
    u16x4 v = { tile[kc * 4 + 0][n], tile[kc * 4 + 1][n],
                tile[kc * 4 + 2][n], tile[kc * 4 + 3][n] };
    *(u16x4*)(out + (size_t)(n0 + n) * K + k0 + kc * 4) = v;
  }
}

// ---------------- GEMM 256x256, BK=64, static-parity double buffer ----------------
__device__ __forceinline__ void store16(float* dst, f32x4 v0, f32x4 v1, f32x4 v2, f32x4 v3) {
  ((f32x4*)dst)[0] = v0; ((f32x4*)dst)[1] = v1; ((f32x4*)dst)[2] = v2; ((f32x4*)dst)[3] = v3;
}
__device__ __forceinline__ void store16(u16* dst, f32x4 v0, f32x4 v1, f32x4 v2, f32x4 v3) {
  u16x8 o0 = { f2bf(v0[0]), f2bf(v0[1]), f2bf(v0[2]), f2bf(v0[3]),
               f2bf(v1[0]), f2bf(v1[1]), f2bf(v1[2]), f2bf(v1[3]) };
  u16x8 o1 = { f2bf(v2[0]), f2bf(v2[1]), f2bf(v2[2]), f2bf(v2[3]),
               f2bf(v3[0]), f2bf(v3[1]), f2bf(v3[2]), f2bf(v3[3]) };
  *(u16x8*)dst = o0; *(u16x8*)(dst + 8) = o1;
}

// C = A * BT^T, bf16 in, fp32 acc. 512 thr (8 waves 2Mx4N). K=1024.
// Staging: single issue point per K-tile, at P4 after the last barrier
// (round-9 schedule — the round-10 split-staging experiment regressed).
template <typename OUT, bool AHB>
__global__ __launch_bounds__(512, 2) void gemm256(const u16* __restrict__ A,
                                                  const u16* __restrict__ BT,
                                                  OUT* __restrict__ C,
                                                  int M, int N, int ntn,
                                                  float* __restrict__ ssq,
                                                  float* __restrict__ ssk) {
  constexpr int ARS   = AHB ? 64 : 1024;     // A row stride (elements)
  constexpr int ASTEP = AHB ? 16384 : 64;    // A K-tile step (elements)
  __shared__ __align__(16) u16 sA0[256 * 64], sA1[256 * 64];
  __shared__ __align__(16) u16 sB0[256 * 64], sB1[256 * 64];
  __shared__ float ssred[4][256];
  const int tid = threadIdx.x, lane = tid & 63, w = tid >> 6;
  const int wm = w >> 2, wn = w & 3;

  int bid = blockIdx.x;
  const int cpx = gridDim.x >> 3;              // grid % 8 == 0 for all our launches
  bid = (bid & 7) * cpx + (bid >> 3);          // XCD swizzle (T1)
  const int tm = (bid / ntn) << 8, tn = (bid % ntn) << 8;

  const u16* srcA[4]; const u16* srcB[4]; int ldsOff[4];
#pragma unroll
  for (int l = 0; l < 4; ++l) {
    const int g = l * 512 + tid;
    const int row = g >> 3, c = g & 7;
    srcA[l] = A + (size_t)tm * 1024 + (size_t)row * ARS + ((c ^ (row & 7)) << 3);
    srcB[l] = BT + (size_t)(tn + row) * 1024 + ((c ^ (row & 7)) << 3);
    ldsOff[l] = g << 4;
  }

#define STAGE(sa, sb, kt) do {                                                 \
    _Pragma("unroll") for (int _l = 0; _l < 4; ++_l) {                         \
      gload16(srcA[_l] + (kt) * ASTEP, (char*)(sa) + ldsOff[_l]);              \
      gload16(srcB[_l] + (kt) * 64, (char*)(sb) + ldsOff[_l]); } } while (0)

  const int swz = (lane & 7) << 4;
  const int r16 = lane & 15;
  const int kb = (lane >> 4) << 4;
#define LDA_(sa, fm, ks) (*(const bf16x8*)((const char*)(sa) + \
    (wm * 128 + (fm) * 16 + r16) * 128 + ((((ks) << 6) | kb) ^ swz)))
#define LDB_(sb, fn, ks) (*(const bf16x8*)((const char*)(sb) + \
    (wn * 64 + (fn) * 16 + r16) * 128 + ((((ks) << 6) | kb) ^ swz)))

  f32x4 acc[8][4];
#pragma unroll
  for (int i = 0; i < 8; ++i)
#pragma unroll
    for (int j = 0; j < 4; ++j) acc[i][j] = (f32x4){0.f, 0.f, 0.f, 0.f};

#define MM(i, j, a_, b_) acc[i][j] = __builtin_amdgcn_mfma_f32_16x16x32_bf16(a_, b_, acc[i][j], 0, 0, 0)

#define KTILE(sa, sb, ...) do {                                                \
  bf16x8 ka[4][2], kb0[2][2], kb1[2][2];                                       \
  _Pragma("unroll") for (int fm = 0; fm < 4; ++fm) {                           \
    ka[fm][0] = LDA_(sa, fm, 0); ka[fm][1] = LDA_(sa, fm, 1); }                \
  _Pragma("unroll") for (int fn = 0; fn < 2; ++fn) {                           \
    kb0[fn][0] = LDB_(sb, fn, 0); kb0[fn][1] = LDB_(sb, fn, 1); }              \
  __builtin_amdgcn_s_barrier();                                                \
  __builtin_amdgcn_s_setprio(1);                                               \
  _Pragma("unroll") for (int fm = 0; fm < 4; ++fm)                             \
    _Pragma("unroll") for (int fn = 0; fn < 2; ++fn) {                         \
      MM(fm, fn, ka[fm][0], kb0[fn][0]); MM(fm, fn, ka[fm][1], kb0[fn][1]); }  \
  __builtin_amdgcn_s_setprio(0);                                               \
  __builtin_amdgcn_s_barrier();                                                \
  _Pragma("unroll") for (int fn = 0; fn < 2; ++fn) {                           \
    kb1[fn][0] = LDB_(sb, 2 + fn, 0); kb1[fn][1] = LDB_(sb, 2 + fn, 1); }      \
  __builtin_amdgcn_s_barrier();                                                \
  __builtin_amdgcn_s_setprio(1);                                               \
  _Pragma("unroll") for (int fm = 0; fm < 4; ++fm)                             \
    _Pragma("unroll") for (int fn = 0; fn < 2; ++fn) {                         \
      MM(fm, 2 + fn, ka[fm][0], kb1[fn][0]); MM(fm, 2 + fn, ka[fm][1], kb1[fn][1]); } \
  __builtin_amdgcn_s_setprio(0);                                               \
  __builtin_amdgcn_s_barrier();                                                \
  _Pragma("unroll") for (int fm = 0; fm < 4; ++fm) {                           \
    ka[fm][0] = LDA_(sa, 4 + fm, 0); ka[fm][1] = LDA_(sa, 4 + fm, 1); }        \
  __builtin_amdgcn_s_barrier();                                                \
  __builtin_amdgcn_s_setprio(1);                                               \
  _Pragma("unroll") for (int fm = 0; fm < 4; ++fm)                             \
    _Pragma("unroll") for (int fn = 0; fn < 2; ++fn) {                         \
      MM(4 + fm, 2 + fn, ka[fm][0], kb1[fn][0]); MM(4 + fm, 2 + fn, ka[fm][1], kb1[fn][1]); } \
  __builtin_amdgcn_s_setprio(0);                                               \
  __builtin_amdgcn_s_barrier();                                                \
  __builtin_amdgcn_sched_barrier(0);                                           \
  __VA_ARGS__;                                                                 \
  __builtin_amdgcn_s_setprio(1);                                               \
  _Pragma("unroll") for (int fm = 0; fm < 4; ++fm)                             \
    _Pragma("unroll") for (int fn = 0; fn < 2; ++fn) {                         \
      MM(4 + fm, fn, ka[fm][0], kb0[fn][0]); MM(4 + fm, fn, ka[fm][1], kb0[fn][1]); } \
  __builtin_amdgcn_s_setprio(0);                                               \
} while (0)

#define TILE_ENTRY(vm) do { __builtin_amdgcn_sched_barrier(0);                 \
    asm volatile("s_waitcnt vmcnt(" #vm ")");                                  \
    __builtin_amdgcn_sched_barrier(0);                                         \
    __builtin_amdgcn_s_barrier();                                              \
    __builtin_amdgcn_sched_barrier(0); } while (0)

  STAGE(sA0, sB0, 0);
  STAGE(sA1, sB1, 1);

#pragma unroll 1
  for (int i = 0; i < 7; ++i) {
    TILE_ENTRY(8);
    KTILE(sA0, sB0, STAGE(sA0, sB0, 2 * i + 2));
    TILE_ENTRY(8);
    KTILE(sA1, sB1, STAGE(sA1, sB1, 2 * i + 3));
  }
  TILE_ENTRY(8);
  KTILE(sA0, sB0, (void)0);
  TILE_ENTRY(0);
  KTILE(sA1, sB1, (void)0);

  __syncthreads();

  const int part = tn >> 10;                  // 0=q 1=k 2=v
  const int cp = tn & 1023;
  const int bg = tm >> 8;
  const int hh = (cp >> 6) + wn;

  // ---- epilogue: per-wave LDS repack -> coalesced wide stores; ss fused ----
  u16* eb = (w == 0) ? sA0 : (w == 1) ? sA0 + 8192 : (w == 2) ? sA1 : (w == 3) ? sA1 + 8192
          : (w == 4) ? sB0 : (w == 5) ? sB0 + 8192 : (w == 6) ? sB1 : sB1 + 8192;
  float* fb = (float*)eb;                     // 16 x 68 f32 region per wave
  const int erow = lane >> 2, eseg = lane & 3;
  OUT* dstb;
  if constexpr (sizeof(OUT) == 2)
    dstb = C + (size_t)part * ((size_t)M_ * C_) + ((size_t)(bg * 16 + hh) * 256) * 64;
  else
    dstb = C + (size_t)tm * N + tn + wn * 64;
#pragma unroll
  for (int fm = 0; fm < 8; ++fm) {
#pragma unroll
    for (int fn = 0; fn < 4; ++fn)
#pragma unroll
      for (int r = 0; r < 4; ++r)
        fb[((lane >> 4) * 4 + r) * 68 + fn * 16 + (lane & 15)] = acc[fm][fn][r];
    asm volatile("s_waitcnt lgkmcnt(0)" ::: "memory");
    const float* src = &fb[erow * 68 + eseg * 16];
    f32x4 v0 = ((const f32x4*)src)[0], v1 = ((const f32x4*)src)[1];
    f32x4 v2 = ((const f32x4*)src)[2], v3 = ((const f32x4*)src)[3];
    if constexpr (sizeof(OUT) == 2) {
      if (part < 2) {                          // ss partial from repacked values
        float s = 0.f;
#pragma unroll
        for (int e = 0; e < 4; ++e)
          s += v0[e] * v0[e] + v1[e] * v1[e] + v2[e] * v2[e] + v3[e] * v3[e];
        s += __shfl_xor(s, 1, 64);
        s += __shfl_xor(s, 2, 64);
        if ((lane & 3) == 0) ssred[wn][wm * 128 + fm * 16 + erow] = s;
      }
    }
    OUT* dst;
    if constexpr (sizeof(OUT) == 2)
      dst = dstb + (size_t)(wm * 128 + fm * 16 + erow) * 64 + eseg * 16;
    else
      dst = dstb + (size_t)(wm * 128 + fm * 16 + erow) * N + eseg * 16;
    store16(dst, v0, v1, v2, v3);
  }
  if constexpr (sizeof(OUT) == 2) {
    if (part < 2) {
      __syncthreads();
      if (tid < 256) {
        float s = ssred[0][tid] + ssred[1][tid] + ssred[2][tid] + ssred[3][tid];
        (part == 0 ? ssq : ssk)[(size_t)(tm + tid) * 4 + (cp >> 8)] = s;
      }
    }
  }
#undef STAGE
#undef LDA_
#undef LDB_
#undef MM
#undef KTILE
#undef TILE_ENTRY
}

// ---------------- block-causal attention (round-9 structure, frozen) ----------------
__global__ __launch_bounds__(256, 2) void attn_kernel(const u16* __restrict__ qkvblk,
                                                      const float* __restrict__ ssq,
                                                      const float* __restrict__ ssk,
                                                      const float* __restrict__ lnw,
                                                      u16* __restrict__ y) {
  const int bid = blockIdx.x;
  const int h = bid & 15;
  const int bg = bid >> 4;
  const size_t rowbase = (size_t)bg * 256;
  const u16* Qb = qkvblk + ((size_t)(bg * 16 + h) * 256) * 64;
  const u16* Kb = Qb + (size_t)M_ * C_;
  const u16* Vb = Qb + 2 * (size_t)M_ * C_;
  u16* Yb = y + ((size_t)(bg * 16 + h) * 256) * 64;

  __shared__ __align__(16) u16 Vt[64 * 256];      // 32KB [hd][k_tok], swizzled
  __shared__ __align__(16) u16 Ps[4][16 * 128];   // 16KB per-wave P-half / y repack
  __shared__ float kscl[256];
  __shared__ float lnsq[64];

  const int tid = threadIdx.x;
  const int lane = tid & 63;
  const int w = tid >> 6;
  const int g = lane >> 4;
  const int qi = lane & 15;

  // ---- prefetch Q fragments + ssq for this wave's 4 balanced q-tiles ----
  const int qts[4] = { w, 7 - w, 8 + w, 15 - w };
  bf16x8 qf0[4], qf1[4];
  f32x4 qv[4];
#pragma unroll
  for (int j = 0; j < 4; ++j) {
    const u16* qrow = Qb + (size_t)(qts[j] * 16 + qi) * 64 + g * 8;
    qf0[j] = *(const bf16x8*)(qrow);
    qf1[j] = *(const bf16x8*)(qrow + 32);
    qv[j] = ((const f32x4*)ssq)[rowbase + qts[j] * 16 + qi];
  }

  // ---- stage V: 8x8 block transpose in-register -> 8 wide LDS writes ----
  {
    const int r0 = (tid >> 3) * 8;        // 8 source rows per thread
    const int d0 = (tid & 7) * 8;         // 8 d-columns per thread
    bf16x8 vr[8];
#pragma unroll
    for (int rr = 0; rr < 8; ++rr)
      vr[rr] = *(const bf16x8*)(Vb + (size_t)(r0 + rr) * 64 + d0);
#pragma unroll
    for (int dd = 0; dd < 8; ++dd) {
      const int d = d0 + dd;
      u16x8 col;
#pragma unroll
      for (int rr = 0; rr < 8; ++rr) col[rr] = (u16)vr[rr][dd];
      const int sw = ((d & 7) ^ ((d >> 3) & 7)) << 4;
      *(u16x8*)((char*)Vt + d * 512 + ((2 * r0) ^ sw)) = col;
    }
    f32x4 kp = ((const f32x4*)ssk)[rowbase + tid];
    kscl[tid] = rsqrtf((kp[0] + kp[1] + kp[2] + kp[3]) * (1.0f / 1024.0f) + 1e-6f);
    if (tid < 64) { float a = lnw[h * 64 + tid]; lnsq[tid] = a * a; }
  }
  __syncthreads();

  // apply rms scale * lnw^2 to prefetched Q fragments
  {
    f32x4 wa0 = *(const f32x4*)&lnsq[g * 8],      wa1 = *(const f32x4*)&lnsq[g * 8 + 4];
    f32x4 wb0 = *(const f32x4*)&lnsq[32 + g * 8], wb1 = *(const f32x4*)&lnsq[32 + g * 8 + 4];
#pragma unroll
    for (int j = 0; j < 4; ++j) {
      const float qsc = rsqrtf((qv[j][0] + qv[j][1] + qv[j][2] + qv[j][3]) * (1.0f / 1024.0f) + 1e-6f);
#pragma unroll
      for (int e = 0; e < 4; ++e) {
        qf0[j][e]     = (short)f2bf(bf2f((u16)qf0[j][e]) * qsc * wa0[e]);
        qf0[j][4 + e] = (short)f2bf(bf2f((u16)qf0[j][4 + e]) * qsc * wa1[e]);
        qf1[j][e]     = (short)f2bf(bf2f((u16)qf1[j][e]) * qsc * wb0[e]);
        qf1[j][4 + e] = (short)f2bf(bf2f((u16)qf1[j][4 + e]) * qsc * wb1[e]);
      }
    }
  }

  char* pb = (char*)Ps[w];
  const int swq = (qi & 7) << 4;

  auto body = [&](int qt, bf16x8 q0, bf16x8 q1) {
    const int q = qt * 16 + qi;

    f32x4 s[16];
#pragma unroll
    for (int n = 0; n < 16; ++n) {
      if (n <= qt) {
        const u16* krow = Kb + (size_t)(n * 16 + qi) * 64 + g * 8;
        bf16x8 ka0 = *(const bf16x8*)(krow);
        bf16x8 ka1 = *(const bf16x8*)(krow + 32);
        f32x4 a = {0.f, 0.f, 0.f, 0.f};
        a = __builtin_amdgcn_mfma_f32_16x16x32_bf16(ka0, q0, a, 0, 0, 0);
        a = __builtin_amdgcn_mfma_f32_16x16x32_bf16(ka1, q1, a, 0, 0, 0);
        s[n] = a;
      }
    }

    float m = -3e38f;
#pragma unroll
    for (int n = 0; n < 16; ++n) if (n <= qt) {
      f32x4 k4 = *(const f32x4*)&kscl[n * 16 + g * 4];
#pragma unroll
      for (int r = 0; r < 4; ++r) {
        const int k_abs = n * 16 + g * 4 + r;
        float v = s[n][r] * 0.125f * k4[r];
        v = (k_abs <= q) ? v : -3e38f;
        s[n][r] = v;
        m = fmaxf(m, v);
      }
    }
    m = fmaxf(m, __shfl_xor(m, 16, 64));
    m = fmaxf(m, __shfl_xor(m, 32, 64));

    float sum = 0.f;
#pragma unroll
    for (int n = 0; n < 16; ++n) if (n <= qt) {
#pragma unroll
      for (int r = 0; r < 4; ++r) {
        float p = __expf(s[n][r] - m);
        s[n][r] = p;
        sum += p;
      }
    }
    sum += __shfl_xor(sum, 16, 64);
    sum += __shfl_xor(sum, 32, 64);

    f32x4 yacc[4];
#pragma unroll
    for (int dn = 0; dn < 4; ++dn) yacc[dn] = (f32x4){0.f, 0.f, 0.f, 0.f};
    const int nkf = qt / 2 + 1;

    // ---- P half 0 (k 0..127) + PV kf 0..3 ----
#pragma unroll
    for (int n = 0; n < 8; ++n) if (n <= qt) {
      u16x4 pk = { f2bf(s[n][0]), f2bf(s[n][1]), f2bf(s[n][2]), f2bf(s[n][3]) };
      *(u16x4*)(pb + qi * 256 + ((n * 32 + g * 8) ^ swq)) = pk;
    }
    if (!(qt & 1) && qt < 7) {      // zero-pad k-tile qt+1 (read by last 32-wide mfma)
      u16x4 z = {0, 0, 0, 0};
      *(u16x4*)(pb + qi * 256 + (((qt + 1) * 32 + g * 8) ^ swq)) = z;
    }
#pragma unroll
    for (int kf = 0; kf < 4; ++kf) if (kf < nkf) {
      bf16x8 pa = *(const bf16x8*)(pb + qi * 256 + ((kf * 64 + g * 16) ^ swq));
#pragma unroll
      for (int dn = 0; dn < 4; ++dn) {
        const int d = dn * 16 + qi;
        const int swv = ((d & 7) ^ ((d >> 3) & 7)) << 4;
        bf16x8 vb = *(const bf16x8*)((const char*)Vt + d * 512 + ((kf * 64 + g * 16) ^ swv));
        yacc[dn] = __builtin_amdgcn_mfma_f32_16x16x32_bf16(pa, vb, yacc[dn], 0, 0, 0);
      }
    }

    // ---- P half 1 (k 128..255) + PV kf 4..7 (per-wave private; DS in-order) ----
    if (qt >= 8) {
#pragma unroll
      for (int n = 8; n < 16; ++n) if (n <= qt) {
        u16x4 pk = { f2bf(s[n][0]), f2bf(s[n][1]), f2bf(s[n][2]), f2bf(s[n][3]) };
        *(u16x4*)(pb + qi * 256 + (((n - 8) * 32 + g * 8) ^ swq)) = pk;
      }
      if (!(qt & 1)) {
        u16x4 z = {0, 0, 0, 0};
        *(u16x4*)(pb + qi * 256 + (((qt - 7) * 32 + g * 8) ^ swq)) = z;
      }
#pragma unroll
      for (int kf = 4; kf < 8; ++kf) if (kf < nkf) {
        bf16x8 pa = *(const bf16x8*)(pb + qi * 256 + (((kf - 4) * 64 + g * 16) ^ swq));
#pragma unroll
        for (int dn = 0; dn < 4; ++dn) {
          const int d = dn * 16 + qi;
          const int swv = ((d & 7) ^ ((d >> 3) & 7)) << 4;
          bf16x8 vb = *(const bf16x8*)((const char*)Vt + d * 512 + ((kf * 64 + g * 16) ^ swv));
          yacc[dn] = __builtin_amdgcn_mfma_f32_16x16x32_bf16(pa, vb, yacc[dn], 0, 0, 0);
        }
      }
    }

    // ---- y repack through pb (private) -> fully contiguous stores ----
#pragma unroll
    for (int r = 0; r < 4; ++r) {
      const float inv = 1.0f / __shfl(sum, g * 4 + r, 64);
      const int row = g * 4 + r;
#pragma unroll
      for (int dn = 0; dn < 4; ++dn)
        *(u16*)(pb + row * 128 + ((dn * 32 + qi * 2) ^ ((row & 7) << 4))) =
            f2bf(yacc[dn][r] * inv);
    }
#pragma unroll
    for (int half = 0; half < 2; ++half) {
      const int row = half * 8 + (lane >> 3);
      const int c16 = lane & 7;
      u16x8 v = *(const u16x8*)(pb + row * 128 + ((c16 * 16) ^ ((row & 7) << 4)));
      *(u16x8*)(Yb + (size_t)(qt * 16 + row) * 64 + c16 * 8) = v;
    }
  };

  body(qts[0], qf0[0], qf1[0]);
  body(qts[1], qf0[1], qf1[1]);
  body(qts[2], qf0[2], qf1[2]);
  body(qts[3], qf0[3], qf1[3]);
}

// ---------------- launch ----------------
extern "C" void kernel_launch(void* const* d_in, const int* in_sizes, int n_in,
                              void* d_out, int out_size, void* d_ws, size_t ws_size,
                              hipStream_t stream) {
  const float* x      = (const float*)d_in[0];   // [16384][1024]
  const float* w_qkv  = (const float*)d_in[1];   // [1024][3072]
  const float* ln_w   = (const float*)d_in[2];   // [1024]
  const float* w_proj = (const float*)d_in[3];   // [1024][1024]
  float* out = (float*)d_out;                    // [16384][1024] fp32

  u16* xb     = (u16*)d_ws;                          // 16384*1024
  u16* wqkvT  = xb + (size_t)M_ * C_;                // 3072*1024 (transposed)
  u16* wprojT = wqkvT + (size_t)N1_ * C_;            // 1024*1024 (transposed)
  u16* qkvblk = wprojT + (size_t)C_ * C_;            // 3 * 16384*1024 head-blocked
  u16* yb     = qkvblk + 3 * (size_t)M_ * C_;        // 16384*1024 head-blocked
  float* ssq  = (float*)(yb + (size_t)M_ * C_);      // 16384*4 f32
  float* ssk  = ssq + (size_t)M_ * 4;                // 16384*4 f32

  prologue_kernel<<<16384 + 768 + 256, 256, 0, stream>>>(x, xb, w_qkv, wqkvT, w_proj, wprojT);

  gemm256<u16, false><<<(M_ / 256) * (N1_ / 256), 512, 0, stream>>>(
      xb, wqkvT, qkvblk, M_, N1_, N1_ / 256, ssq, ssk);
  attn_kernel<<<64 * 16, 256, 0, stream>>>(qkvblk, ssq, ssk, ln_w, yb);
  gemm256<float, true><<<(M_ / 256) * (C_ / 256), 512, 0, stream>>>(
      yb, wprojT, out, M_, C_, C_ / 256, nullptr, nullptr);
}